// Round 2
// baseline (5901.973 us; speedup 1.0000x reference)
//
#include <hip/hip_runtime.h>
#include <math.h>

namespace {

constexpr int Na = 50000, Np = 100000, L = 2, E = 150000;

__device__ inline float geluf(float x){ return 0.5f*x*(1.0f + erff(x*0.7071067811865476f)); }

__device__ inline float bf2f(unsigned short u){ return __uint_as_float(((unsigned)u) << 16); }
__device__ inline unsigned short f2bf(float f){
  unsigned u = __float_as_uint(f);
  u += 0x7FFFu + ((u >> 16) & 1u);   // round-to-nearest-even
  return (unsigned short)(u >> 16);
}

struct StF32 {
  using T = float;
  static __device__ float ld(const T* p){ return *p; }
  static __device__ void st(T* p, float v){ *p = v; }
};
struct StBF16 {
  using T = unsigned short;
  static __device__ float ld(const T* p){ return bf2f(*p); }
  static __device__ void st(T* p, float v){ *p = f2bf(v); }
};

__device__ inline void atomicMaxF(float* addr, float v){
  if (v >= 0.0f) atomicMax((int*)addr, __float_as_int(v));
  else           atomicMin((unsigned int*)addr, __float_as_uint(v));
}

__global__ void fill_kernel(float* __restrict__ p, float v, int n){
  int i = blockIdx.x*256 + threadIdx.x;
  int stride = gridDim.x*256;
  for (; i < n; i += stride) p[i] = v;
}

__global__ void diag_kernel(float* o, float v){
  if (threadIdx.x == 0 && blockIdx.x == 0) o[0] = v;
}

// Fold rel_a/rel_m into K/V projection weights.
// effw layout: [c=l*4+t*2+kv][f=128][j=128], j = h*16+e2. effb: [c][128].
__global__ void eff_w_kernel(const float* __restrict__ kqv_w, const float* __restrict__ kqv_b,
                             const float* __restrict__ rel_a, const float* __restrict__ rel_m,
                             float* __restrict__ effw, float* __restrict__ effb){
  int idx = blockIdx.x*256 + threadIdx.x;
  if (idx >= 2*2*2*128*128) return;
  int j = idx & 127; int f = (idx >> 7) & 127; int c = idx >> 14;
  int kv = c & 1, t = (c >> 1) & 1, l = c >> 2;
  int h = j >> 4, e2 = j & 15;
  int i = (kv == 0) ? 0 : 2;  // K uses i=0, V uses i=2
  const float* W = kqv_w + ((size_t)(((l*2 + t)*3 + i)*128) + f)*128 + h*16;
  const float* A = ((kv == 0) ? rel_a : rel_m) + ((size_t)(l*2 + t)*8 + h)*256; // edge type == src type
  float acc = 0.f;
  #pragma unroll
  for (int d = 0; d < 16; ++d) acc += W[d]*A[d*16 + e2];
  effw[(size_t)c*16384 + f*128 + j] = acc;
  if (f == 0){
    const float* B = kqv_b + (size_t)((l*2 + t)*3 + i)*128 + h*16;
    float ab = 0.f;
    #pragma unroll
    for (int d = 0; d < 16; ++d) ab += B[d]*A[d*16 + e2];
    effb[c*128 + j] = ab;
  }
}

// Y[N,BN] = act(X[N,128]) @ W[128,BN] + bias, optional gelu-in, relu-out, gated skip.
// 256 threads, 64 rows/block. Storage types: SIn for X, SOut for Y and skip_x.
template<int BN, int TM, int TN, typename SIn, typename SOut>
__global__ void linear_kernel(const typename SIn::T* __restrict__ X,
                              const float* __restrict__ W,
                              const float* __restrict__ bias,
                              typename SOut::T* __restrict__ Y, int N,
                              int gelu_in, int relu_out,
                              const typename SOut::T* __restrict__ skip_x,
                              const float* __restrict__ skip_s){
  __shared__ __align__(16) float Xs[64][128];
  int row0 = blockIdx.x*64;
  for (int idx = threadIdx.x; idx < 64*128; idx += 256){
    int r = idx >> 7, k = idx & 127;
    int gr = row0 + r;
    float v = (gr < N) ? SIn::ld(&X[(size_t)gr*128 + k]) : 0.f;
    if (gelu_in) v = geluf(v);
    Xs[r][k] = v;
  }
  __syncthreads();
  constexpr int TC = BN / TN;
  int tx = threadIdx.x % TC, ty = threadIdx.x / TC;
  int c0 = tx*TN, r0 = ty*TM;
  float acc[TM][TN] = {};
  for (int k = 0; k < 128; k += 4){
    float4 xv[TM];
    #pragma unroll
    for (int i = 0; i < TM; ++i) xv[i] = *reinterpret_cast<const float4*>(&Xs[r0+i][k]);
    #pragma unroll
    for (int kk = 0; kk < 4; ++kk){
      float4 w4 = *reinterpret_cast<const float4*>(W + (size_t)(k+kk)*BN + c0);
      #pragma unroll
      for (int i = 0; i < TM; ++i){
        float xk = (kk==0) ? xv[i].x : (kk==1) ? xv[i].y : (kk==2) ? xv[i].z : xv[i].w;
        acc[i][0] += xk*w4.x; acc[i][1] += xk*w4.y;
        acc[i][2] += xk*w4.z; acc[i][3] += xk*w4.w;
      }
    }
  }
  float g = 1.f, og = 0.f;
  if (skip_s){ float sv = *skip_s; g = 1.f/(1.f + expf(-sv)); og = 1.f - g; }
  #pragma unroll
  for (int i = 0; i < TM; ++i){
    int gr = row0 + r0 + i;
    if (gr >= N) continue;
    #pragma unroll
    for (int j = 0; j < TN; ++j){
      float y = acc[i][j] + bias[c0+j];
      if (relu_out) y = fmaxf(y, 0.f);
      if (skip_x) y = g*y + og*SOut::ld(&skip_x[(size_t)gr*128 + c0 + j]);
      SOut::st(&Y[(size_t)gr*BN + c0 + j], y);
    }
  }
}

template<typename S>
__global__ void alpha_kernel(const typename S::T* __restrict__ Q, const typename S::T* __restrict__ Kn,
                             const int* __restrict__ src, const int* __restrict__ dst,
                             const float* __restrict__ relp,
                             float* __restrict__ alpha, float* __restrict__ mbuf, int nE){
  int idx = blockIdx.x*256 + threadIdx.x;
  if (idx >= nE*8) return;
  int h = idx & 7, e = idx >> 3;
  int s = src[e], d = dst[e];
  const typename S::T* q = Q  + (size_t)d*128 + h*16;
  const typename S::T* k = Kn + (size_t)s*128 + h*16;
  float a = 0.f;
  #pragma unroll
  for (int i = 0; i < 16; ++i) a += S::ld(&q[i]) * S::ld(&k[i]);
  a *= relp[h]*0.25f;  // * rel_p * 1/sqrt(16)
  alpha[idx] = a;
  atomicMaxF(&mbuf[(size_t)d*8 + h], a);
}

__global__ void expsum_kernel(float* __restrict__ alpha, const int* __restrict__ dst,
                              const float* __restrict__ mbuf, float* __restrict__ sbuf, int nE){
  int idx = blockIdx.x*256 + threadIdx.x;
  if (idx >= nE*8) return;
  int h = idx & 7, e = idx >> 3;
  int d = dst[e];
  float ex = expf(alpha[idx] - mbuf[(size_t)d*8 + h]);
  alpha[idx] = ex;
  atomicAdd(&sbuf[(size_t)d*8 + h], ex);
}

template<typename S, bool PK>
__global__ void scatter_kernel(const float* __restrict__ alpha, const typename S::T* __restrict__ Vn,
                               const int* __restrict__ src, const int* __restrict__ dst,
                               const float* __restrict__ sbuf, void* __restrict__ agg, int nE){
  int idx = blockIdx.x*256 + threadIdx.x;
  if (idx >= nE*8) return;
  int h = idx & 7, e = idx >> 3;
  int s = src[e], d = dst[e];
  float w = alpha[idx] / (sbuf[(size_t)d*8 + h] + 1e-16f);
  const typename S::T* v = Vn + (size_t)s*128 + h*16;
  if constexpr (!PK){
    float* o = (float*)agg + (size_t)d*128 + h*16;
    #pragma unroll
    for (int i = 0; i < 16; ++i) atomicAdd(&o[i], w*S::ld(&v[i]));
  } else {
    unsigned* o = (unsigned*)agg + (size_t)d*64 + h*8;
    #pragma unroll
    for (int i = 0; i < 8; ++i){
      float a0 = w*S::ld(&v[2*i]), a1 = w*S::ld(&v[2*i+1]);
      unsigned cur = o[i];
      while (true){
        float x0 = bf2f((unsigned short)(cur & 0xffff)) + a0;
        float x1 = bf2f((unsigned short)(cur >> 16)) + a1;
        unsigned nv = (unsigned)f2bf(x0) | ((unsigned)f2bf(x1) << 16);
        unsigned prev = atomicCAS(&o[i], cur, nv);
        if (prev == cur) break;
        cur = prev;
      }
    }
  }
}

struct Ptrs {
  const float *x_author, *x_paper, *win_w, *win_b, *kqv_w, *kqv_b, *a_w, *a_b;
  const float *skip, *rel_a, *rel_m, *rel_p, *out_w, *out_b;
  const int *src0, *dst0, *src1, *dst1;
};

template<typename S, bool PK>
static void run_pipeline(const Ptrs& P, float* d_out, char* ws, hipStream_t stream){
  using T = typename S::T;
  size_t off = 0;
  auto alloc = [&](size_t bytes) -> void* {
    void* p = ws + off;
    off += (bytes + 255) & ~(size_t)255;
    return p;
  };
  T* X0 = (T*)alloc((size_t)Na*128*sizeof(T));
  T* X1 = (T*)alloc((size_t)Np*128*sizeof(T));
  T* A0 = (T*)alloc((size_t)Na*128*sizeof(T));
  T* A1 = (T*)alloc((size_t)Np*128*sizeof(T));
  T* B0 = (T*)alloc((size_t)Na*128*sizeof(T));
  T* B1 = (T*)alloc((size_t)Np*128*sizeof(T));
  float* alpha0 = (float*)alloc((size_t)E*8*4);
  float* alpha1 = (float*)alloc((size_t)E*8*4);
  float* m0 = (float*)alloc((size_t)Na*8*4);
  float* s0 = (float*)alloc((size_t)Na*8*4);
  float* m1 = (float*)alloc((size_t)Np*8*4);
  float* s1 = (float*)alloc((size_t)Np*8*4);
  float* effw = (float*)alloc((size_t)8*16384*4);
  float* effb = (float*)alloc((size_t)8*128*4);

  auto cdiv = [](int a, int b){ return (a+b-1)/b; };
  const int ge = cdiv(E*8, 256);
  const int ga = cdiv(Na, 64), gp = cdiv(Np, 64);

  eff_w_kernel<<<512, 256, 0, stream>>>(P.kqv_w, P.kqv_b, P.rel_a, P.rel_m, effw, effb);

  // Input projections + relu (fp32 input -> S storage)
  linear_kernel<128,8,4,StF32,S><<<ga,256,0,stream>>>(P.x_author, P.win_w,       P.win_b,     X0, Na, 0,1, nullptr, nullptr);
  linear_kernel<128,8,4,StF32,S><<<gp,256,0,stream>>>(P.x_paper,  P.win_w+16384, P.win_b+128, X1, Np, 0,1, nullptr, nullptr);

  for (int l = 0; l < L; ++l){
    // Q per type -> A
    linear_kernel<128,8,4,S,S><<<ga,256,0,stream>>>(X0, P.kqv_w + (size_t)((l*2+0)*3+1)*16384, P.kqv_b + ((l*2+0)*3+1)*128, A0, Na, 0,0,nullptr,nullptr);
    linear_kernel<128,8,4,S,S><<<gp,256,0,stream>>>(X1, P.kqv_w + (size_t)((l*2+1)*3+1)*16384, P.kqv_b + ((l*2+1)*3+1)*128, A1, Np, 0,0,nullptr,nullptr);
    // Kn per type (rel_a folded) -> B
    linear_kernel<128,8,4,S,S><<<ga,256,0,stream>>>(X0, effw + (size_t)(l*4+0)*16384, effb + (l*4+0)*128, B0, Na, 0,0,nullptr,nullptr);
    linear_kernel<128,8,4,S,S><<<gp,256,0,stream>>>(X1, effw + (size_t)(l*4+2)*16384, effb + (l*4+2)*128, B1, Np, 0,0,nullptr,nullptr);
    // softmax state
    fill_kernel<<<1024,256,0,stream>>>(m0, -INFINITY, Na*8);
    fill_kernel<<<1024,256,0,stream>>>(m1, -INFINITY, Np*8);
    fill_kernel<<<1024,256,0,stream>>>(s0, 0.f, Na*8);
    fill_kernel<<<1024,256,0,stream>>>(s1, 0.f, Np*8);
    // attention scores + segment max, then exp + segment sum
    alpha_kernel<S><<<ge,256,0,stream>>>(A1, B0, P.src0, P.dst0, P.rel_p + (l*2+0)*8, alpha0, m1, E);
    alpha_kernel<S><<<ge,256,0,stream>>>(A0, B1, P.src1, P.dst1, P.rel_p + (l*2+1)*8, alpha1, m0, E);
    expsum_kernel<<<ge,256,0,stream>>>(alpha0, P.dst0, m1, s1, E);
    expsum_kernel<<<ge,256,0,stream>>>(alpha1, P.dst1, m0, s0, E);
    // Vn per type (rel_m folded) -> B (overwrite Kn; alphas already computed)
    linear_kernel<128,8,4,S,S><<<ga,256,0,stream>>>(X0, effw + (size_t)(l*4+1)*16384, effb + (l*4+1)*128, B0, Na, 0,0,nullptr,nullptr);
    linear_kernel<128,8,4,S,S><<<gp,256,0,stream>>>(X1, effw + (size_t)(l*4+3)*16384, effb + (l*4+3)*128, B1, Np, 0,0,nullptr,nullptr);
    // zero agg (reuse A; Q dead). byte count / 4 as floats.
    fill_kernel<<<2048,256,0,stream>>>((float*)A0, 0.f, (int)((size_t)Na*128*sizeof(T)/4));
    fill_kernel<<<2048,256,0,stream>>>((float*)A1, 0.f, (int)((size_t)Np*128*sizeof(T)/4));
    // normalize + weighted scatter into agg
    scatter_kernel<S,PK><<<ge,256,0,stream>>>(alpha0, B0, P.src0, P.dst0, s1, A1, E);
    scatter_kernel<S,PK><<<ge,256,0,stream>>>(alpha1, B1, P.src1, P.dst1, s0, A0, E);
    // gelu(agg) @ a_w + a_b, gated skip with X -> X (in place; per-element same-thread RMW)
    linear_kernel<128,8,4,S,S><<<ga,256,0,stream>>>(A0, P.a_w + (size_t)(l*2+0)*16384, P.a_b + (l*2+0)*128, X0, Na, 1,0, X0, P.skip + (l*2+0));
    linear_kernel<128,8,4,S,S><<<gp,256,0,stream>>>(A1, P.a_w + (size_t)(l*2+1)*16384, P.a_b + (l*2+1)*128, X1, Np, 1,0, X1, P.skip + (l*2+1));
  }

  // final classifier: [Na,128] @ [128,64] + b -> d_out (fp32)
  linear_kernel<64,4,4,S,StF32><<<ga,256,0,stream>>>(X0, P.out_w, P.out_b, d_out, Na, 0,0,nullptr,nullptr);
}

static size_t plan_bytes(size_t sT){
  auto al = [](size_t x){ return (x + 255) & ~(size_t)255; };
  size_t pair = al((size_t)Na*128*sT) + al((size_t)Np*128*sT);
  return 3*pair + 2*al((size_t)E*8*4) + al((size_t)Na*8*4)*2 + al((size_t)Np*8*4)*2
         + al((size_t)8*16384*4) + al((size_t)8*128*4);
}

} // namespace

extern "C" void kernel_launch(void* const* d_in, const int* in_sizes, int n_in,
                              void* d_out, int out_size, void* d_ws, size_t ws_size,
                              hipStream_t stream){
  Ptrs P;
  P.x_author = (const float*)d_in[0];
  P.x_paper  = (const float*)d_in[1];
  P.win_w = (const float*)d_in[2];
  P.win_b = (const float*)d_in[3];
  P.kqv_w = (const float*)d_in[4];
  P.kqv_b = (const float*)d_in[5];
  P.a_w   = (const float*)d_in[6];
  P.a_b   = (const float*)d_in[7];
  P.skip  = (const float*)d_in[8];
  P.rel_a = (const float*)d_in[9];
  P.rel_m = (const float*)d_in[10];
  P.rel_p = (const float*)d_in[11];
  P.out_w = (const float*)d_in[12];
  P.out_b = (const float*)d_in[13];
  P.src0 = (const int*)d_in[14];
  P.dst0 = (const int*)d_in[15];
  P.src1 = (const int*)d_in[16];
  P.dst1 = (const int*)d_in[17];

  if (ws_size >= plan_bytes(4)){
    run_pipeline<StF32,false>(P, (float*)d_out, (char*)d_ws, stream);
  } else if (ws_size >= plan_bytes(2)){
    run_pipeline<StBF16,true>(P, (float*)d_out, (char*)d_ws, stream);
  } else {
    // Diagnostic: absmax will read ~= ws_size in MB.
    diag_kernel<<<1,1,0,stream>>>((float*)d_out, (float)((double)ws_size/1.0e6));
  }
}

// Round 3
// 1790.271 us; speedup vs baseline: 3.2967x; 3.2967x over previous
//
#include <hip/hip_runtime.h>
#include <math.h>

namespace {

constexpr int Na = 50000, Np = 100000, L = 2, E = 150000;

__device__ inline float geluf(float x){ return 0.5f*x*(1.0f + erff(x*0.7071067811865476f)); }

__device__ inline float bf2f(unsigned short u){ return __uint_as_float(((unsigned)u) << 16); }
__device__ inline unsigned short f2bf(float f){
  unsigned u = __float_as_uint(f);
  u += 0x7FFFu + ((u >> 16) & 1u);   // round-to-nearest-even
  return (unsigned short)(u >> 16);
}

struct StF32 {
  using T = float;
  static __device__ float ld(const T* p){ return *p; }
  static __device__ void st(T* p, float v){ *p = v; }
  static __device__ void ld16(const T* __restrict__ p, float* o){
    const float4* q = reinterpret_cast<const float4*>(p);
    #pragma unroll
    for (int i = 0; i < 4; ++i){
      float4 v = q[i];
      o[4*i] = v.x; o[4*i+1] = v.y; o[4*i+2] = v.z; o[4*i+3] = v.w;
    }
  }
};
struct StBF16 {
  using T = unsigned short;
  static __device__ float ld(const T* p){ return bf2f(*p); }
  static __device__ void st(T* p, float v){ *p = f2bf(v); }
  static __device__ void ld16(const T* __restrict__ p, float* o){
    const uint4* q = reinterpret_cast<const uint4*>(p);
    #pragma unroll
    for (int half = 0; half < 2; ++half){
      uint4 u = q[half];
      unsigned w0 = u.x, w1 = u.y, w2 = u.z, w3 = u.w;
      o[half*8+0] = bf2f((unsigned short)(w0 & 0xffff));
      o[half*8+1] = bf2f((unsigned short)(w0 >> 16));
      o[half*8+2] = bf2f((unsigned short)(w1 & 0xffff));
      o[half*8+3] = bf2f((unsigned short)(w1 >> 16));
      o[half*8+4] = bf2f((unsigned short)(w2 & 0xffff));
      o[half*8+5] = bf2f((unsigned short)(w2 >> 16));
      o[half*8+6] = bf2f((unsigned short)(w3 & 0xffff));
      o[half*8+7] = bf2f((unsigned short)(w3 >> 16));
    }
  }
};

__global__ void zero_int_kernel(int* __restrict__ p, int n){
  int i = blockIdx.x*256 + threadIdx.x;
  int stride = gridDim.x*256;
  for (; i < n; i += stride) p[i] = 0;
}

__global__ void diag_kernel(float* o, float v){
  if (threadIdx.x == 0 && blockIdx.x == 0) o[0] = v;
}

__global__ void hist_kernel(const int* __restrict__ dst, int* __restrict__ counts, int nE){
  int e = blockIdx.x*256 + threadIdx.x;
  if (e >= nE) return;
  atomicAdd(&counts[dst[e]], 1);
}

// Single-block exclusive scan: counts[i] (in) -> rp[i]=prefix, counts[i]=prefix (cursor), rp[n]=total.
__global__ void scan_kernel(int* __restrict__ counts, int* __restrict__ rp, int n){
  __shared__ int part[1024];
  int t = threadIdx.x;
  int chunk = (n + 1023) >> 10;
  int b = t*chunk, e = min(b + chunk, n);
  int s = 0;
  for (int i = b; i < e; ++i) s += counts[i];
  part[t] = s;
  __syncthreads();
  for (int off = 1; off < 1024; off <<= 1){
    int add = (t >= off) ? part[t-off] : 0;
    __syncthreads();
    part[t] += add;
    __syncthreads();
  }
  int run = part[t] - s;   // exclusive base for this thread's chunk
  for (int i = b; i < e; ++i){
    int c = counts[i];
    rp[i] = run;
    counts[i] = run;       // cursor for fill pass
    run += c;
  }
  if (t == 1023) rp[n] = part[1023];
}

__global__ void fill_slots_kernel(const int* __restrict__ src, const int* __restrict__ dst,
                                  int* __restrict__ cursor, int* __restrict__ slots, int nE){
  int e = blockIdx.x*256 + threadIdx.x;
  if (e >= nE) return;
  int slot = atomicAdd(&cursor[dst[e]], 1);
  slots[slot] = src[e];
}

// Fold rel_a/rel_m into K/V projection weights.
// effw layout: [c=l*4+t*2+kv][f=128][j=128], j = h*16+e2. effb: [c][128].
__global__ void eff_w_kernel(const float* __restrict__ kqv_w, const float* __restrict__ kqv_b,
                             const float* __restrict__ rel_a, const float* __restrict__ rel_m,
                             float* __restrict__ effw, float* __restrict__ effb){
  int idx = blockIdx.x*256 + threadIdx.x;
  if (idx >= 2*2*2*128*128) return;
  int j = idx & 127; int f = (idx >> 7) & 127; int c = idx >> 14;
  int kv = c & 1, t = (c >> 1) & 1, l = c >> 2;
  int h = j >> 4, e2 = j & 15;
  int i = (kv == 0) ? 0 : 2;  // K uses i=0, V uses i=2
  const float* W = kqv_w + ((size_t)(((l*2 + t)*3 + i)*128) + f)*128 + h*16;
  const float* A = ((kv == 0) ? rel_a : rel_m) + ((size_t)(l*2 + t)*8 + h)*256; // edge type == src type
  float acc = 0.f;
  #pragma unroll
  for (int d = 0; d < 16; ++d) acc += W[d]*A[d*16 + e2];
  effw[(size_t)c*16384 + f*128 + j] = acc;
  if (f == 0){
    const float* B = kqv_b + (size_t)((l*2 + t)*3 + i)*128 + h*16;
    float ab = 0.f;
    #pragma unroll
    for (int d = 0; d < 16; ++d) ab += B[d]*A[d*16 + e2];
    effb[c*128 + j] = ab;
  }
}

// Y[N,BN] = act(X[N,128]) @ W[128,BN] + bias, optional gelu-in, relu-out, gated skip.
template<int BN, int TM, int TN, typename SIn, typename SOut>
__global__ void linear_kernel(const typename SIn::T* __restrict__ X,
                              const float* __restrict__ W,
                              const float* __restrict__ bias,
                              typename SOut::T* __restrict__ Y, int N,
                              int gelu_in, int relu_out,
                              const typename SOut::T* __restrict__ skip_x,
                              const float* __restrict__ skip_s){
  __shared__ __align__(16) float Xs[64][128];
  int row0 = blockIdx.x*64;
  for (int idx = threadIdx.x; idx < 64*128; idx += 256){
    int r = idx >> 7, k = idx & 127;
    int gr = row0 + r;
    float v = (gr < N) ? SIn::ld(&X[(size_t)gr*128 + k]) : 0.f;
    if (gelu_in) v = geluf(v);
    Xs[r][k] = v;
  }
  __syncthreads();
  constexpr int TC = BN / TN;
  int tx = threadIdx.x % TC, ty = threadIdx.x / TC;
  int c0 = tx*TN, r0 = ty*TM;
  float acc[TM][TN] = {};
  for (int k = 0; k < 128; k += 4){
    float4 xv[TM];
    #pragma unroll
    for (int i = 0; i < TM; ++i) xv[i] = *reinterpret_cast<const float4*>(&Xs[r0+i][k]);
    #pragma unroll
    for (int kk = 0; kk < 4; ++kk){
      float4 w4 = *reinterpret_cast<const float4*>(W + (size_t)(k+kk)*BN + c0);
      #pragma unroll
      for (int i = 0; i < TM; ++i){
        float xk = (kk==0) ? xv[i].x : (kk==1) ? xv[i].y : (kk==2) ? xv[i].z : xv[i].w;
        acc[i][0] += xk*w4.x; acc[i][1] += xk*w4.y;
        acc[i][2] += xk*w4.z; acc[i][3] += xk*w4.w;
      }
    }
  }
  float g = 1.f, og = 0.f;
  if (skip_s){ float sv = *skip_s; g = 1.f/(1.f + expf(-sv)); og = 1.f - g; }
  #pragma unroll
  for (int i = 0; i < TM; ++i){
    int gr = row0 + r0 + i;
    if (gr >= N) continue;
    #pragma unroll
    for (int j = 0; j < TN; ++j){
      float y = acc[i][j] + bias[c0+j];
      if (relu_out) y = fmaxf(y, 0.f);
      if (skip_x) y = g*y + og*SOut::ld(&skip_x[(size_t)gr*128 + c0 + j]);
      SOut::st(&Y[(size_t)gr*BN + c0 + j], y);
    }
  }
}

// Fused attention: one thread per (dst node, head). Online softmax over CSR in-edges,
// gathers K/V rows, writes normalized aggregate IN PLACE over the Q buffer.
template<typename SX, typename SKV>
__global__ void attn_gather_kernel(typename SX::T* __restrict__ QA,
                                   const typename SKV::T* __restrict__ K,
                                   const typename SKV::T* __restrict__ V,
                                   const int* __restrict__ rp, const int* __restrict__ slots,
                                   const float* __restrict__ relp, int N){
  int idx = blockIdx.x*256 + threadIdx.x;
  if (idx >= N*8) return;
  int h = idx & 7, n = idx >> 3;
  float q[16];
  SX::ld16(&QA[(size_t)n*128 + h*16], q);
  float scale_h = relp[h]*0.25f;   // rel_p * 1/sqrt(16)
  float m = -INFINITY, s = 0.f, acc[16];
  #pragma unroll
  for (int i = 0; i < 16; ++i) acc[i] = 0.f;
  int b = rp[n], e = rp[n+1];
  for (int j = b; j < e; ++j){
    int sv = slots[j];
    float kf[16], vf[16];
    SKV::ld16(&K[(size_t)sv*128 + h*16], kf);
    float a = 0.f;
    #pragma unroll
    for (int i = 0; i < 16; ++i) a += q[i]*kf[i];
    a *= scale_h;
    float mn = fmaxf(m, a);
    float c = expf(m - mn);    // first iter: exp(-inf) = 0
    float p = expf(a - mn);
    SKV::ld16(&V[(size_t)sv*128 + h*16], vf);
    s = s*c + p;
    #pragma unroll
    for (int i = 0; i < 16; ++i) acc[i] = acc[i]*c + p*vf[i];
    m = mn;
  }
  float inv = 1.f/(s + 1e-16f);
  #pragma unroll
  for (int i = 0; i < 16; ++i) SX::st(&QA[(size_t)n*128 + h*16 + i], acc[i]*inv);
}

struct Ptrs {
  const float *x_author, *x_paper, *win_w, *win_b, *kqv_w, *kqv_b, *a_w, *a_b;
  const float *skip, *rel_a, *rel_m, *rel_p, *out_w, *out_b;
  const int *src0, *dst0, *src1, *dst1;
};

template<typename SX, typename SKV>
static void run_pipeline(const Ptrs& P, float* d_out, char* ws, hipStream_t stream){
  using TX = typename SX::T;
  using TK = typename SKV::T;
  size_t off = 0;
  auto alloc = [&](size_t bytes) -> void* {
    void* p = ws + off;
    off += (bytes + 255) & ~(size_t)255;
    return p;
  };
  TX* X0 = (TX*)alloc((size_t)Na*128*sizeof(TX));
  TX* X1 = (TX*)alloc((size_t)Np*128*sizeof(TX));
  TX* Q0 = (TX*)alloc((size_t)Na*128*sizeof(TX));   // Q -> agg in place
  TX* Q1 = (TX*)alloc((size_t)Np*128*sizeof(TX));
  TK* K0 = (TK*)alloc((size_t)Na*128*sizeof(TK));
  TK* K1 = (TK*)alloc((size_t)Np*128*sizeof(TK));
  TK* V0 = (TK*)alloc((size_t)Na*128*sizeof(TK));
  TK* V1 = (TK*)alloc((size_t)Np*128*sizeof(TK));
  float* effw = (float*)alloc((size_t)8*16384*4);
  float* effb = (float*)alloc((size_t)8*128*4);
  int* rp0   = (int*)alloc((size_t)(Np+1)*4);   // edge type 0: dst = papers
  int* cur0  = (int*)alloc((size_t)Np*4);
  int* slot0 = (int*)alloc((size_t)E*4);
  int* rp1   = (int*)alloc((size_t)(Na+1)*4);   // edge type 1: dst = authors
  int* cur1  = (int*)alloc((size_t)Na*4);
  int* slot1 = (int*)alloc((size_t)E*4);

  auto cdiv = [](int a, int b){ return (a+b-1)/b; };
  const int geE = cdiv(E, 256);
  const int ga = cdiv(Na, 64), gp = cdiv(Np, 64);

  eff_w_kernel<<<512, 256, 0, stream>>>(P.kqv_w, P.kqv_b, P.rel_a, P.rel_m, effw, effb);

  // ---- CSR build (graph static across layers) ----
  zero_int_kernel<<<512,256,0,stream>>>(cur0, Np);
  zero_int_kernel<<<512,256,0,stream>>>(cur1, Na);
  hist_kernel<<<geE,256,0,stream>>>(P.dst0, cur0, E);
  hist_kernel<<<geE,256,0,stream>>>(P.dst1, cur1, E);
  scan_kernel<<<1,1024,0,stream>>>(cur0, rp0, Np);
  scan_kernel<<<1,1024,0,stream>>>(cur1, rp1, Na);
  fill_slots_kernel<<<geE,256,0,stream>>>(P.src0, P.dst0, cur0, slot0, E);
  fill_slots_kernel<<<geE,256,0,stream>>>(P.src1, P.dst1, cur1, slot1, E);

  // ---- input projections + relu ----
  linear_kernel<128,8,4,StF32,SX><<<ga,256,0,stream>>>(P.x_author, P.win_w,       P.win_b,     X0, Na, 0,1, nullptr, nullptr);
  linear_kernel<128,8,4,StF32,SX><<<gp,256,0,stream>>>(P.x_paper,  P.win_w+16384, P.win_b+128, X1, Np, 0,1, nullptr, nullptr);

  for (int l = 0; l < L; ++l){
    // Q per type
    linear_kernel<128,8,4,SX,SX><<<ga,256,0,stream>>>(X0, P.kqv_w + (size_t)((l*2+0)*3+1)*16384, P.kqv_b + ((l*2+0)*3+1)*128, Q0, Na, 0,0,nullptr,nullptr);
    linear_kernel<128,8,4,SX,SX><<<gp,256,0,stream>>>(X1, P.kqv_w + (size_t)((l*2+1)*3+1)*16384, P.kqv_b + ((l*2+1)*3+1)*128, Q1, Np, 0,0,nullptr,nullptr);
    // K (rel_a folded), V (rel_m folded)
    linear_kernel<128,8,4,SX,SKV><<<ga,256,0,stream>>>(X0, effw + (size_t)(l*4+0)*16384, effb + (l*4+0)*128, K0, Na, 0,0,nullptr,nullptr);
    linear_kernel<128,8,4,SX,SKV><<<gp,256,0,stream>>>(X1, effw + (size_t)(l*4+2)*16384, effb + (l*4+2)*128, K1, Np, 0,0,nullptr,nullptr);
    linear_kernel<128,8,4,SX,SKV><<<ga,256,0,stream>>>(X0, effw + (size_t)(l*4+1)*16384, effb + (l*4+1)*128, V0, Na, 0,0,nullptr,nullptr);
    linear_kernel<128,8,4,SX,SKV><<<gp,256,0,stream>>>(X1, effw + (size_t)(l*4+3)*16384, effb + (l*4+3)*128, V1, Np, 0,0,nullptr,nullptr);
    // fused attention: type 0 (author->paper) into Q1, type 1 (paper->author) into Q0
    attn_gather_kernel<SX,SKV><<<cdiv(Np*8,256),256,0,stream>>>(Q1, K0, V0, rp0, slot0, P.rel_p + (l*2+0)*8, Np);
    attn_gather_kernel<SX,SKV><<<cdiv(Na*8,256),256,0,stream>>>(Q0, K1, V1, rp1, slot1, P.rel_p + (l*2+1)*8, Na);
    // gelu(agg) @ a_w + a_b, gated skip with X -> X (in place)
    linear_kernel<128,8,4,SX,SX><<<ga,256,0,stream>>>(Q0, P.a_w + (size_t)(l*2+0)*16384, P.a_b + (l*2+0)*128, X0, Na, 1,0, X0, P.skip + (l*2+0));
    linear_kernel<128,8,4,SX,SX><<<gp,256,0,stream>>>(Q1, P.a_w + (size_t)(l*2+1)*16384, P.a_b + (l*2+1)*128, X1, Np, 1,0, X1, P.skip + (l*2+1));
  }

  // final classifier: [Na,128] @ [128,64] + b -> d_out (fp32)
  linear_kernel<64,4,4,SX,StF32><<<ga,256,0,stream>>>(X0, P.out_w, P.out_b, d_out, Na, 0,0,nullptr,nullptr);
}

static size_t plan_bytes(size_t sX, size_t sKV){
  auto al = [](size_t x){ return (x + 255) & ~(size_t)255; };
  size_t t = 0;
  t += 2*(al((size_t)Na*128*sX) + al((size_t)Np*128*sX));    // X, Q/agg
  t += 2*(al((size_t)Na*128*sKV) + al((size_t)Np*128*sKV));  // K, V
  t += al((size_t)8*16384*4) + al((size_t)8*128*4);
  t += al((size_t)(Np+1)*4) + al((size_t)Np*4) + al((size_t)E*4);
  t += al((size_t)(Na+1)*4) + al((size_t)Na*4) + al((size_t)E*4);
  return t;
}

} // namespace

extern "C" void kernel_launch(void* const* d_in, const int* in_sizes, int n_in,
                              void* d_out, int out_size, void* d_ws, size_t ws_size,
                              hipStream_t stream){
  Ptrs P;
  P.x_author = (const float*)d_in[0];
  P.x_paper  = (const float*)d_in[1];
  P.win_w = (const float*)d_in[2];
  P.win_b = (const float*)d_in[3];
  P.kqv_w = (const float*)d_in[4];
  P.kqv_b = (const float*)d_in[5];
  P.a_w   = (const float*)d_in[6];
  P.a_b   = (const float*)d_in[7];
  P.skip  = (const float*)d_in[8];
  P.rel_a = (const float*)d_in[9];
  P.rel_m = (const float*)d_in[10];
  P.rel_p = (const float*)d_in[11];
  P.out_w = (const float*)d_in[12];
  P.out_b = (const float*)d_in[13];
  P.src0 = (const int*)d_in[14];
  P.dst0 = (const int*)d_in[15];
  P.src1 = (const int*)d_in[16];
  P.dst1 = (const int*)d_in[17];

  if (ws_size >= plan_bytes(4, 4)){
    run_pipeline<StF32,StF32>(P, (float*)d_out, (char*)d_ws, stream);
  } else if (ws_size >= plan_bytes(4, 2)){
    run_pipeline<StF32,StBF16>(P, (float*)d_out, (char*)d_ws, stream);
  } else if (ws_size >= plan_bytes(2, 2)){
    run_pipeline<StBF16,StBF16>(P, (float*)d_out, (char*)d_ws, stream);
  } else {
    diag_kernel<<<1,1,0,stream>>>((float*)d_out, (float)((double)ws_size/1.0e6));
  }
}

// Round 4
// 1495.897 us; speedup vs baseline: 3.9454x; 1.1968x over previous
//
#include <hip/hip_runtime.h>
#include <math.h>

namespace {

constexpr int Na = 50000, Np = 100000, L = 2, E = 150000;
constexpr int SCAN_TILE = 2048;   // 256 threads x 8

__device__ inline float geluf(float x){ return 0.5f*x*(1.0f + erff(x*0.7071067811865476f)); }

__device__ inline float bf2f(unsigned short u){ return __uint_as_float(((unsigned)u) << 16); }
__device__ inline unsigned short f2bf(float f){
  unsigned u = __float_as_uint(f);
  u += 0x7FFFu + ((u >> 16) & 1u);   // round-to-nearest-even
  return (unsigned short)(u >> 16);
}

struct StF32 {
  using T = float;
  static __device__ float ld(const T* p){ return *p; }
  static __device__ void st(T* p, float v){ *p = v; }
  static __device__ void ld16(const T* __restrict__ p, float* o){
    const float4* q = reinterpret_cast<const float4*>(p);
    #pragma unroll
    for (int i = 0; i < 4; ++i){
      float4 v = q[i];
      o[4*i] = v.x; o[4*i+1] = v.y; o[4*i+2] = v.z; o[4*i+3] = v.w;
    }
  }
};
struct StBF16 {
  using T = unsigned short;
  static __device__ float ld(const T* p){ return bf2f(*p); }
  static __device__ void st(T* p, float v){ *p = f2bf(v); }
  static __device__ void ld16(const T* __restrict__ p, float* o){
    const uint4* q = reinterpret_cast<const uint4*>(p);
    #pragma unroll
    for (int half = 0; half < 2; ++half){
      uint4 u = q[half];
      unsigned w0 = u.x, w1 = u.y, w2 = u.z, w3 = u.w;
      o[half*8+0] = bf2f((unsigned short)(w0 & 0xffff));
      o[half*8+1] = bf2f((unsigned short)(w0 >> 16));
      o[half*8+2] = bf2f((unsigned short)(w1 & 0xffff));
      o[half*8+3] = bf2f((unsigned short)(w1 >> 16));
      o[half*8+4] = bf2f((unsigned short)(w2 & 0xffff));
      o[half*8+5] = bf2f((unsigned short)(w2 >> 16));
      o[half*8+6] = bf2f((unsigned short)(w3 & 0xffff));
      o[half*8+7] = bf2f((unsigned short)(w3 >> 16));
    }
  }
};

__global__ void zero_int_kernel(int* __restrict__ p, int n){
  int i = blockIdx.x*256 + threadIdx.x;
  int stride = gridDim.x*256;
  for (; i < n; i += stride) p[i] = 0;
}

__global__ void diag_kernel(float* o, float v){
  if (threadIdx.x == 0 && blockIdx.x == 0) o[0] = v;
}

__global__ void hist_kernel(const int* __restrict__ dst, int* __restrict__ counts, int nE){
  int e = blockIdx.x*256 + threadIdx.x;
  if (e >= nE) return;
  atomicAdd(&counts[dst[e]], 1);
}

// ---- multi-block exclusive scan (3 phases) ----
__global__ void scan_a(const int* __restrict__ counts, int* __restrict__ bsum, int n){
  int base = blockIdx.x*SCAN_TILE;
  int s = 0;
  for (int i = threadIdx.x; i < SCAN_TILE; i += 256){
    int g = base + i;
    s += (g < n) ? counts[g] : 0;
  }
  __shared__ int red[256];
  red[threadIdx.x] = s;
  __syncthreads();
  for (int off = 128; off > 0; off >>= 1){
    if (threadIdx.x < off) red[threadIdx.x] += red[threadIdx.x + off];
    __syncthreads();
  }
  if (threadIdx.x == 0) bsum[blockIdx.x] = red[0];
}

__global__ void scan_b(int* __restrict__ bsum, int nb){
  __shared__ int sh[1024];
  int t = threadIdx.x;
  int v = (t < nb) ? bsum[t] : 0;
  sh[t] = v;
  __syncthreads();
  for (int off = 1; off < 1024; off <<= 1){
    int add = (t >= off) ? sh[t-off] : 0;
    __syncthreads();
    sh[t] += add;
    __syncthreads();
  }
  if (t < nb) bsum[t] = sh[t] - v;   // exclusive
}

// Reads counts, writes rp[g] (exclusive prefix) and counts[g] (=same, as fill cursor), rp[n]=total.
__global__ void scan_c(int* __restrict__ counts, const int* __restrict__ bsum,
                       int* __restrict__ rp, int n){
  int base = blockIdx.x*SCAN_TILE;
  __shared__ int sh[SCAN_TILE];
  for (int i = threadIdx.x; i < SCAN_TILE; i += 256){
    int g = base + i;
    sh[i] = (g < n) ? counts[g] : 0;
  }
  __syncthreads();
  int t = threadIdx.x;
  int loc[8], s = 0;
  #pragma unroll
  for (int i = 0; i < 8; ++i){ loc[i] = s; s += sh[t*8 + i]; }
  __shared__ int red[256];
  red[t] = s;
  __syncthreads();
  for (int off = 1; off < 256; off <<= 1){
    int add = (t >= off) ? red[t-off] : 0;
    __syncthreads();
    red[t] += add;
    __syncthreads();
  }
  int texcl = red[t] - s + bsum[blockIdx.x];
  #pragma unroll
  for (int i = 0; i < 8; ++i){
    int g = base + t*8 + i;
    if (g < n){
      int v = texcl + loc[i];
      rp[g] = v;
      counts[g] = v;           // cursor for fill pass
      if (g == n-1) rp[n] = v + sh[t*8 + i];
    }
  }
}

__global__ void fill_slots_kernel(const int* __restrict__ src, const int* __restrict__ dst,
                                  int* __restrict__ cursor, int* __restrict__ slots, int nE){
  int e = blockIdx.x*256 + threadIdx.x;
  if (e >= nE) return;
  int slot = atomicAdd(&cursor[dst[e]], 1);
  slots[slot] = src[e];
}

// Fold rel_a/rel_m into K/V projection weights.
// effw layout: [c=l*4+t*2+kv][f=128][j=128], j = h*16+e2. effb: [c][128].
__global__ void eff_w_kernel(const float* __restrict__ kqv_w, const float* __restrict__ kqv_b,
                             const float* __restrict__ rel_a, const float* __restrict__ rel_m,
                             float* __restrict__ effw, float* __restrict__ effb){
  int idx = blockIdx.x*256 + threadIdx.x;
  if (idx >= 2*2*2*128*128) return;
  int j = idx & 127; int f = (idx >> 7) & 127; int c = idx >> 14;
  int kv = c & 1, t = (c >> 1) & 1, l = c >> 2;
  int h = j >> 4, e2 = j & 15;
  int i = (kv == 0) ? 0 : 2;  // K uses i=0, V uses i=2
  const float* W = kqv_w + ((size_t)(((l*2 + t)*3 + i)*128) + f)*128 + h*16;
  const float* A = ((kv == 0) ? rel_a : rel_m) + ((size_t)(l*2 + t)*8 + h)*256; // edge type == src type
  float acc = 0.f;
  #pragma unroll
  for (int d = 0; d < 16; ++d) acc += W[d]*A[d*16 + e2];
  effw[(size_t)c*16384 + f*128 + j] = acc;
  if (f == 0){
    const float* B = kqv_b + (size_t)((l*2 + t)*3 + i)*128 + h*16;
    float ab = 0.f;
    #pragma unroll
    for (int d = 0; d < 16; ++d) ab += B[d]*A[d*16 + e2];
    effb[c*128 + j] = ab;
  }
}

// Y[N,BN] = act(X[N,128]) @ W[128,BN] + bias, optional gelu-in, relu-out, gated skip.
template<int BN, int TM, int TN, typename SIn, typename SOut>
__global__ void linear_kernel(const typename SIn::T* __restrict__ X,
                              const float* __restrict__ W,
                              const float* __restrict__ bias,
                              typename SOut::T* __restrict__ Y, int N,
                              int gelu_in, int relu_out,
                              const typename SOut::T* __restrict__ skip_x,
                              const float* __restrict__ skip_s){
  __shared__ __align__(16) float Xs[64][128];
  int row0 = blockIdx.x*64;
  for (int idx = threadIdx.x; idx < 64*128; idx += 256){
    int r = idx >> 7, k = idx & 127;
    int gr = row0 + r;
    float v = (gr < N) ? SIn::ld(&X[(size_t)gr*128 + k]) : 0.f;
    if (gelu_in) v = geluf(v);
    Xs[r][k] = v;
  }
  __syncthreads();
  constexpr int TC = BN / TN;
  int tx = threadIdx.x % TC, ty = threadIdx.x / TC;
  int c0 = tx*TN, r0 = ty*TM;
  float acc[TM][TN] = {};
  for (int k = 0; k < 128; k += 4){
    float4 xv[TM];
    #pragma unroll
    for (int i = 0; i < TM; ++i) xv[i] = *reinterpret_cast<const float4*>(&Xs[r0+i][k]);
    #pragma unroll
    for (int kk = 0; kk < 4; ++kk){
      float4 w4 = *reinterpret_cast<const float4*>(W + (size_t)(k+kk)*BN + c0);
      #pragma unroll
      for (int i = 0; i < TM; ++i){
        float xk = (kk==0) ? xv[i].x : (kk==1) ? xv[i].y : (kk==2) ? xv[i].z : xv[i].w;
        acc[i][0] += xk*w4.x; acc[i][1] += xk*w4.y;
        acc[i][2] += xk*w4.z; acc[i][3] += xk*w4.w;
      }
    }
  }
  float g = 1.f, og = 0.f;
  if (skip_s){ float sv = *skip_s; g = 1.f/(1.f + expf(-sv)); og = 1.f - g; }
  #pragma unroll
  for (int i = 0; i < TM; ++i){
    int gr = row0 + r0 + i;
    if (gr >= N) continue;
    #pragma unroll
    for (int j = 0; j < TN; ++j){
      float y = acc[i][j] + bias[c0+j];
      if (relu_out) y = fmaxf(y, 0.f);
      if (skip_x) y = g*y + og*SOut::ld(&skip_x[(size_t)gr*128 + c0 + j]);
      SOut::st(&Y[(size_t)gr*BN + c0 + j], y);
    }
  }
}

// Fused attention: one thread per (dst node, head). Online softmax over CSR in-edges,
// gathers K/V rows, writes normalized aggregate IN PLACE over the Q buffer.
template<typename SX, typename SKV>
__global__ void attn_gather_kernel(typename SX::T* __restrict__ QA,
                                   const typename SKV::T* __restrict__ K,
                                   const typename SKV::T* __restrict__ V,
                                   const int* __restrict__ rp, const int* __restrict__ slots,
                                   const float* __restrict__ relp, int N){
  int idx = blockIdx.x*256 + threadIdx.x;
  if (idx >= N*8) return;
  int h = idx & 7, n = idx >> 3;
  float q[16];
  SX::ld16(&QA[(size_t)n*128 + h*16], q);
  float scale_h = relp[h]*0.25f;   // rel_p * 1/sqrt(16)
  float m = -INFINITY, s = 0.f, acc[16];
  #pragma unroll
  for (int i = 0; i < 16; ++i) acc[i] = 0.f;
  int b = rp[n], e = rp[n+1];
  for (int j = b; j < e; ++j){
    int sv = slots[j];
    float kf[16], vf[16];
    SKV::ld16(&K[(size_t)sv*128 + h*16], kf);
    float a = 0.f;
    #pragma unroll
    for (int i = 0; i < 16; ++i) a += q[i]*kf[i];
    a *= scale_h;
    float mn = fmaxf(m, a);
    float c = expf(m - mn);    // first iter: exp(-inf) = 0
    float p = expf(a - mn);
    SKV::ld16(&V[(size_t)sv*128 + h*16], vf);
    s = s*c + p;
    #pragma unroll
    for (int i = 0; i < 16; ++i) acc[i] = acc[i]*c + p*vf[i];
    m = mn;
  }
  float inv = 1.f/(s + 1e-16f);
  #pragma unroll
  for (int i = 0; i < 16; ++i) SX::st(&QA[(size_t)n*128 + h*16 + i], acc[i]*inv);
}

struct Ptrs {
  const float *x_author, *x_paper, *win_w, *win_b, *kqv_w, *kqv_b, *a_w, *a_b;
  const float *skip, *rel_a, *rel_m, *rel_p, *out_w, *out_b;
  const int *src0, *dst0, *src1, *dst1;
};

template<typename SX, typename SKV>
static void run_pipeline(const Ptrs& P, float* d_out, char* ws, hipStream_t stream){
  using TX = typename SX::T;
  using TK = typename SKV::T;
  size_t off = 0;
  auto alloc = [&](size_t bytes) -> void* {
    void* p = ws + off;
    off += (bytes + 255) & ~(size_t)255;
    return p;
  };
  TX* X0 = (TX*)alloc((size_t)Na*128*sizeof(TX));
  TX* X1 = (TX*)alloc((size_t)Np*128*sizeof(TX));
  TX* Q0 = (TX*)alloc((size_t)Na*128*sizeof(TX));   // Q -> agg in place
  TX* Q1 = (TX*)alloc((size_t)Np*128*sizeof(TX));
  TK* K0 = (TK*)alloc((size_t)Na*128*sizeof(TK));
  TK* K1 = (TK*)alloc((size_t)Np*128*sizeof(TK));
  TK* V0 = (TK*)alloc((size_t)Na*128*sizeof(TK));
  TK* V1 = (TK*)alloc((size_t)Np*128*sizeof(TK));
  float* effw = (float*)alloc((size_t)8*16384*4);
  float* effb = (float*)alloc((size_t)8*128*4);
  int* rp0   = (int*)alloc((size_t)(Np+1)*4);   // edge type 0: dst = papers
  int* cur0  = (int*)alloc((size_t)Np*4);
  int* slot0 = (int*)alloc((size_t)E*4);
  int* rp1   = (int*)alloc((size_t)(Na+1)*4);   // edge type 1: dst = authors
  int* cur1  = (int*)alloc((size_t)Na*4);
  int* slot1 = (int*)alloc((size_t)E*4);
  int* bsum  = (int*)alloc((size_t)1024*4);

  auto cdiv = [](int a, int b){ return (a+b-1)/b; };
  const int geE = cdiv(E, 256);
  const int ga = cdiv(Na, 64), gp = cdiv(Np, 64);
  const int sb0 = cdiv(Np, SCAN_TILE), sb1 = cdiv(Na, SCAN_TILE);

  eff_w_kernel<<<512, 256, 0, stream>>>(P.kqv_w, P.kqv_b, P.rel_a, P.rel_m, effw, effb);

  // ---- CSR build (graph static across layers) ----
  zero_int_kernel<<<512,256,0,stream>>>(cur0, Np);
  zero_int_kernel<<<512,256,0,stream>>>(cur1, Na);
  hist_kernel<<<geE,256,0,stream>>>(P.dst0, cur0, E);
  hist_kernel<<<geE,256,0,stream>>>(P.dst1, cur1, E);
  scan_a<<<sb0,256,0,stream>>>(cur0, bsum, Np);
  scan_b<<<1,1024,0,stream>>>(bsum, sb0);
  scan_c<<<sb0,256,0,stream>>>(cur0, bsum, rp0, Np);
  scan_a<<<sb1,256,0,stream>>>(cur1, bsum, Na);
  scan_b<<<1,1024,0,stream>>>(bsum, sb1);
  scan_c<<<sb1,256,0,stream>>>(cur1, bsum, rp1, Na);
  fill_slots_kernel<<<geE,256,0,stream>>>(P.src0, P.dst0, cur0, slot0, E);
  fill_slots_kernel<<<geE,256,0,stream>>>(P.src1, P.dst1, cur1, slot1, E);

  // ---- input projections + relu ----
  linear_kernel<128,8,4,StF32,SX><<<ga,256,0,stream>>>(P.x_author, P.win_w,       P.win_b,     X0, Na, 0,1, nullptr, nullptr);
  linear_kernel<128,8,4,StF32,SX><<<gp,256,0,stream>>>(P.x_paper,  P.win_w+16384, P.win_b+128, X1, Np, 0,1, nullptr, nullptr);

  for (int l = 0; l < L; ++l){
    // Q per type
    linear_kernel<128,8,4,SX,SX><<<ga,256,0,stream>>>(X0, P.kqv_w + (size_t)((l*2+0)*3+1)*16384, P.kqv_b + ((l*2+0)*3+1)*128, Q0, Na, 0,0,nullptr,nullptr);
    linear_kernel<128,8,4,SX,SX><<<gp,256,0,stream>>>(X1, P.kqv_w + (size_t)((l*2+1)*3+1)*16384, P.kqv_b + ((l*2+1)*3+1)*128, Q1, Np, 0,0,nullptr,nullptr);
    // K (rel_a folded), V (rel_m folded)
    linear_kernel<128,8,4,SX,SKV><<<ga,256,0,stream>>>(X0, effw + (size_t)(l*4+0)*16384, effb + (l*4+0)*128, K0, Na, 0,0,nullptr,nullptr);
    linear_kernel<128,8,4,SX,SKV><<<gp,256,0,stream>>>(X1, effw + (size_t)(l*4+2)*16384, effb + (l*4+2)*128, K1, Np, 0,0,nullptr,nullptr);
    linear_kernel<128,8,4,SX,SKV><<<ga,256,0,stream>>>(X0, effw + (size_t)(l*4+1)*16384, effb + (l*4+1)*128, V0, Na, 0,0,nullptr,nullptr);
    linear_kernel<128,8,4,SX,SKV><<<gp,256,0,stream>>>(X1, effw + (size_t)(l*4+3)*16384, effb + (l*4+3)*128, V1, Np, 0,0,nullptr,nullptr);
    // fused attention: type 0 (author->paper) into Q1, type 1 (paper->author) into Q0
    attn_gather_kernel<SX,SKV><<<cdiv(Np*8,256),256,0,stream>>>(Q1, K0, V0, rp0, slot0, P.rel_p + (l*2+0)*8, Np);
    attn_gather_kernel<SX,SKV><<<cdiv(Na*8,256),256,0,stream>>>(Q0, K1, V1, rp1, slot1, P.rel_p + (l*2+1)*8, Na);
    // gelu(agg) @ a_w + a_b, gated skip with X -> X (in place)
    linear_kernel<128,8,4,SX,SX><<<ga,256,0,stream>>>(Q0, P.a_w + (size_t)(l*2+0)*16384, P.a_b + (l*2+0)*128, X0, Na, 1,0, X0, P.skip + (l*2+0));
    linear_kernel<128,8,4,SX,SX><<<gp,256,0,stream>>>(Q1, P.a_w + (size_t)(l*2+1)*16384, P.a_b + (l*2+1)*128, X1, Np, 1,0, X1, P.skip + (l*2+1));
  }

  // final classifier: [Na,128] @ [128,64] + b -> d_out (fp32)
  linear_kernel<64,4,4,SX,StF32><<<ga,256,0,stream>>>(X0, P.out_w, P.out_b, d_out, Na, 0,0,nullptr,nullptr);
}

static size_t plan_bytes(size_t sX, size_t sKV){
  auto al = [](size_t x){ return (x + 255) & ~(size_t)255; };
  size_t t = 0;
  t += 2*(al((size_t)Na*128*sX) + al((size_t)Np*128*sX));    // X, Q/agg
  t += 2*(al((size_t)Na*128*sKV) + al((size_t)Np*128*sKV));  // K, V
  t += al((size_t)8*16384*4) + al((size_t)8*128*4);
  t += al((size_t)(Np+1)*4) + al((size_t)Np*4) + al((size_t)E*4);
  t += al((size_t)(Na+1)*4) + al((size_t)Na*4) + al((size_t)E*4);
  t += al((size_t)1024*4);
  return t;
}

} // namespace

extern "C" void kernel_launch(void* const* d_in, const int* in_sizes, int n_in,
                              void* d_out, int out_size, void* d_ws, size_t ws_size,
                              hipStream_t stream){
  Ptrs P;
  P.x_author = (const float*)d_in[0];
  P.x_paper  = (const float*)d_in[1];
  P.win_w = (const float*)d_in[2];
  P.win_b = (const float*)d_in[3];
  P.kqv_w = (const float*)d_in[4];
  P.kqv_b = (const float*)d_in[5];
  P.a_w   = (const float*)d_in[6];
  P.a_b   = (const float*)d_in[7];
  P.skip  = (const float*)d_in[8];
  P.rel_a = (const float*)d_in[9];
  P.rel_m = (const float*)d_in[10];
  P.rel_p = (const float*)d_in[11];
  P.out_w = (const float*)d_in[12];
  P.out_b = (const float*)d_in[13];
  P.src0 = (const int*)d_in[14];
  P.dst0 = (const int*)d_in[15];
  P.src1 = (const int*)d_in[16];
  P.dst1 = (const int*)d_in[17];

  if (ws_size >= plan_bytes(4, 4)){
    run_pipeline<StF32,StF32>(P, (float*)d_out, (char*)d_ws, stream);
  } else if (ws_size >= plan_bytes(4, 2)){
    run_pipeline<StF32,StBF16>(P, (float*)d_out, (char*)d_ws, stream);
  } else if (ws_size >= plan_bytes(2, 2)){
    run_pipeline<StBF16,StBF16>(P, (float*)d_out, (char*)d_ws, stream);
  } else {
    diag_kernel<<<1,1,0,stream>>>((float*)d_out, (float)((double)ws_size/1.0e6));
  }
}

// Round 6
// 562.424 us; speedup vs baseline: 10.4938x; 2.6597x over previous
//
#include <hip/hip_runtime.h>
#include <math.h>

namespace {

constexpr int Na = 50000, Np = 100000, L = 2, E = 150000;
constexpr int SCAN_TILE = 2048;

typedef __attribute__((ext_vector_type(8))) short short8v;
typedef __attribute__((ext_vector_type(4))) float f32x4;

__device__ inline float geluf(float x){ return 0.5f*x*(1.0f + erff(x*0.7071067811865476f)); }

__device__ inline float bf2f(unsigned short u){ return __uint_as_float(((unsigned)u) << 16); }
__device__ inline unsigned short f2bf(float f){
  unsigned u = __float_as_uint(f);
  u += 0x7FFFu + ((u >> 16) & 1u);   // round-to-nearest-even
  return (unsigned short)(u >> 16);
}

struct StF32 {
  using T = float;
  static __device__ float ld(const T* p){ return *p; }
  static __device__ void st(T* p, float v){ *p = v; }
  static __device__ short8v ld8(const T* __restrict__ p){
    float4 lo = *reinterpret_cast<const float4*>(p);
    float4 hi = *reinterpret_cast<const float4*>(p+4);
    short8v v;
    v[0]=(short)f2bf(lo.x); v[1]=(short)f2bf(lo.y); v[2]=(short)f2bf(lo.z); v[3]=(short)f2bf(lo.w);
    v[4]=(short)f2bf(hi.x); v[5]=(short)f2bf(hi.y); v[6]=(short)f2bf(hi.z); v[7]=(short)f2bf(hi.w);
    return v;
  }
  static __device__ void ld16(const T* __restrict__ p, float* o){
    const float4* q = reinterpret_cast<const float4*>(p);
    #pragma unroll
    for (int i = 0; i < 4; ++i){
      float4 v = q[i];
      o[4*i] = v.x; o[4*i+1] = v.y; o[4*i+2] = v.z; o[4*i+3] = v.w;
    }
  }
};
struct StBF16 {
  using T = unsigned short;
  static __device__ float ld(const T* p){ return bf2f(*p); }
  static __device__ void st(T* p, float v){ *p = f2bf(v); }
  static __device__ short8v ld8(const T* __restrict__ p){
    return *reinterpret_cast<const short8v*>(p);
  }
  static __device__ void ld16(const T* __restrict__ p, float* o){
    const uint4* q = reinterpret_cast<const uint4*>(p);
    #pragma unroll
    for (int half = 0; half < 2; ++half){
      uint4 u = q[half];
      o[half*8+0] = bf2f((unsigned short)(u.x & 0xffff));
      o[half*8+1] = bf2f((unsigned short)(u.x >> 16));
      o[half*8+2] = bf2f((unsigned short)(u.y & 0xffff));
      o[half*8+3] = bf2f((unsigned short)(u.y >> 16));
      o[half*8+4] = bf2f((unsigned short)(u.z & 0xffff));
      o[half*8+5] = bf2f((unsigned short)(u.z >> 16));
      o[half*8+6] = bf2f((unsigned short)(u.w & 0xffff));
      o[half*8+7] = bf2f((unsigned short)(u.w >> 16));
    }
  }
};

__global__ void zero_int_kernel(int* __restrict__ p, int n){
  int i = blockIdx.x*256 + threadIdx.x;
  int stride = gridDim.x*256;
  for (; i < n; i += stride) p[i] = 0;
}

__global__ void diag_kernel(float* o, float v){
  if (threadIdx.x == 0 && blockIdx.x == 0) o[0] = v;
}

__global__ void hist_kernel(const int* __restrict__ dst, int* __restrict__ counts, int nE){
  int e = blockIdx.x*256 + threadIdx.x;
  if (e >= nE) return;
  atomicAdd(&counts[dst[e]], 1);
}

// ---- multi-block exclusive scan (3 phases) ----
__global__ void scan_a(const int* __restrict__ counts, int* __restrict__ bsum, int n){
  int base = blockIdx.x*SCAN_TILE;
  int s = 0;
  for (int i = threadIdx.x; i < SCAN_TILE; i += 256){
    int g = base + i;
    s += (g < n) ? counts[g] : 0;
  }
  __shared__ int red[256];
  red[threadIdx.x] = s;
  __syncthreads();
  for (int off = 128; off > 0; off >>= 1){
    if (threadIdx.x < off) red[threadIdx.x] += red[threadIdx.x + off];
    __syncthreads();
  }
  if (threadIdx.x == 0) bsum[blockIdx.x] = red[0];
}

__global__ void scan_b(int* __restrict__ bsum, int nb){
  __shared__ int sh[1024];
  int t = threadIdx.x;
  int v = (t < nb) ? bsum[t] : 0;
  sh[t] = v;
  __syncthreads();
  for (int off = 1; off < 1024; off <<= 1){
    int add = (t >= off) ? sh[t-off] : 0;
    __syncthreads();
    sh[t] += add;
    __syncthreads();
  }
  if (t < nb) bsum[t] = sh[t] - v;   // exclusive
}

__global__ void scan_c(int* __restrict__ counts, const int* __restrict__ bsum,
                       int* __restrict__ rp, int n){
  int base = blockIdx.x*SCAN_TILE;
  __shared__ int sh[SCAN_TILE];
  for (int i = threadIdx.x; i < SCAN_TILE; i += 256){
    int g = base + i;
    sh[i] = (g < n) ? counts[g] : 0;
  }
  __syncthreads();
  int t = threadIdx.x;
  int loc[8], s = 0;
  #pragma unroll
  for (int i = 0; i < 8; ++i){ loc[i] = s; s += sh[t*8 + i]; }
  __shared__ int red[256];
  red[t] = s;
  __syncthreads();
  for (int off = 1; off < 256; off <<= 1){
    int add = (t >= off) ? red[t-off] : 0;
    __syncthreads();
    red[t] += add;
    __syncthreads();
  }
  int texcl = red[t] - s + bsum[blockIdx.x];
  #pragma unroll
  for (int i = 0; i < 8; ++i){
    int g = base + t*8 + i;
    if (g < n){
      int v = texcl + loc[i];
      rp[g] = v;
      counts[g] = v;           // cursor for fill pass
      if (g == n-1) rp[n] = v + sh[t*8 + i];
    }
  }
}

__global__ void fill_slots_kernel(const int* __restrict__ src, const int* __restrict__ dst,
                                  int* __restrict__ cursor, int* __restrict__ slots, int nE){
  int e = blockIdx.x*256 + threadIdx.x;
  if (e >= nE) return;
  int slot = atomicAdd(&cursor[dst[e]], 1);
  slots[slot] = src[e];
}

// Fold rel_a/rel_m into K/V projection weights (fp32).
// effw layout: [c=l*4+t*2+kv][f=128][j=128]. effb: [c][128].
__global__ void eff_w_kernel(const float* __restrict__ kqv_w, const float* __restrict__ kqv_b,
                             const float* __restrict__ rel_a, const float* __restrict__ rel_m,
                             float* __restrict__ effw, float* __restrict__ effb){
  int idx = blockIdx.x*256 + threadIdx.x;
  if (idx >= 2*2*2*128*128) return;
  int j = idx & 127; int f = (idx >> 7) & 127; int c = idx >> 14;
  int kv = c & 1, t = (c >> 1) & 1, l = c >> 2;
  int h = j >> 4, e2 = j & 15;
  int i = (kv == 0) ? 0 : 2;  // K uses i=0, V uses i=2
  const float* W = kqv_w + ((size_t)(((l*2 + t)*3 + i)*128) + f)*128 + h*16;
  const float* A = ((kv == 0) ? rel_a : rel_m) + ((size_t)(l*2 + t)*8 + h)*256;
  float acc = 0.f;
  #pragma unroll
  for (int d = 0; d < 16; ++d) acc += W[d]*A[d*16 + e2];
  effw[(size_t)c*16384 + f*128 + j] = acc;
  if (f == 0){
    const float* B = kqv_b + (size_t)((l*2 + t)*3 + i)*128 + h*16;
    float ab = 0.f;
    #pragma unroll
    for (int d = 0; d < 16; ++d) ab += B[d]*A[d*16 + e2];
    effb[c*128 + j] = ab;
  }
}

// Convert 19 weight matrices fp32 [k][n] -> bf16 transposed [n][128(k)], slot s at wbf+s*16384.
struct PrepSrc { const float* s[19]; };
__global__ void prep_w_kernel(PrepSrc P, unsigned short* __restrict__ wbf){
  int idx = blockIdx.x*256 + threadIdx.x;
  if (idx >= 19*16384) return;
  int s = idx >> 14, j = idx & 16383;
  int n = j >> 7, k = j & 127;
  int nc = (s == 18) ? 64 : 128;
  if (n >= nc) return;
  wbf[(size_t)s*16384 + n*128 + k] = f2bf(P.s[s][(size_t)k*nc + n]);
}

// MFMA GEMM: Y[N,BN] = epi( act(X[N,128]) @ W[128,BN] + bias ).
// WT = bf16 W transposed [BN][128]. 256 threads, 128 rows/block, 4 waves (2x2).
// LDS tiles XOR-swizzled at 16B granularity: chunk c16 (0..15) of row r stored at c16^(r&7).
template<int BN, int GELU_IN, int RELU_OUT, int SKIP, typename SIn, typename SOut>
__global__ __launch_bounds__(256) void gemm_kernel(
    const typename SIn::T* __restrict__ X,
    const unsigned short* __restrict__ WT,
    const float* __restrict__ bias,
    typename SOut::T* __restrict__ Y, int N,
    const typename SOut::T* __restrict__ skip_x,
    const float* __restrict__ skip_s)
{
  __shared__ __align__(16) short As[128*128];
  __shared__ __align__(16) short Bs[BN*128];
  const int t = threadIdx.x;
  const int row0 = blockIdx.x*128;
  // stage A (bf16, swizzled): 128 rows x 16 chunks of 8 bf16
  for (int c = t; c < 128*16; c += 256){
    int r = c >> 4, c16 = c & 15;
    int gr = row0 + r;
    short8v v;
    if (gr < N){
      v = SIn::ld8(&X[(size_t)gr*128 + c16*8]);
      if (GELU_IN){
        #pragma unroll
        for (int i = 0; i < 8; ++i){
          float f = geluf(bf2f((unsigned short)v[i]));
          v[i] = (short)f2bf(f);
        }
      }
    } else {
      v = (short8v)0;
    }
    *reinterpret_cast<short8v*>(&As[r*128 + ((c16 ^ (r&7))<<3)]) = v;
  }
  // stage B (already bf16 [BN][128])
  for (int c = t; c < BN*16; c += 256){
    int r = c >> 4, c16 = c & 15;
    short8v v = *reinterpret_cast<const short8v*>(&WT[r*128 + c16*8]);
    *reinterpret_cast<short8v*>(&Bs[r*128 + ((c16 ^ (r&7))<<3)]) = v;
  }
  __syncthreads();
  const int lane = t & 63, wid = t >> 6;
  const int wm = wid >> 1, wn = wid & 1;
  constexpr int NR = BN/32;          // fragments per wave along N (wave covers BN/2 cols)
  const int lr = lane & 15, lk = lane >> 4;
  f32x4 acc[4][NR] = {};
  #pragma unroll
  for (int kk = 0; kk < 4; ++kk){
    int kc = kk*4 + lk;              // 16B chunk index along K (0..15)
    short8v a[4], b[NR];
    #pragma unroll
    for (int m = 0; m < 4; ++m){
      int r = wm*64 + m*16 + lr;
      a[m] = *reinterpret_cast<const short8v*>(&As[r*128 + ((kc ^ (r&7))<<3)]);
    }
    #pragma unroll
    for (int n = 0; n < NR; ++n){
      int r = wn*(BN/2) + n*16 + lr;
      b[n] = *reinterpret_cast<const short8v*>(&Bs[r*128 + ((kc ^ (r&7))<<3)]);
    }
    #pragma unroll
    for (int m = 0; m < 4; ++m)
      #pragma unroll
      for (int n = 0; n < NR; ++n)
        acc[m][n] = __builtin_amdgcn_mfma_f32_16x16x32_bf16(a[m], b[n], acc[m][n], 0, 0, 0);
  }
  float g = 1.f, og = 0.f;
  if (SKIP){ float sv = *skip_s; g = 1.f/(1.f + expf(-sv)); og = 1.f - g; }
  #pragma unroll
  for (int m = 0; m < 4; ++m){
    #pragma unroll
    for (int r = 0; r < 4; ++r){
      int row = row0 + wm*64 + m*16 + lk*4 + r;
      if (row >= N) continue;
      #pragma unroll
      for (int n = 0; n < NR; ++n){
        int col = wn*(BN/2) + n*16 + lr;
        float y = acc[m][n][r] + bias[col];
        if (RELU_OUT) y = fmaxf(y, 0.f);
        if (SKIP) y = g*y + og*SOut::ld(&skip_x[(size_t)row*BN + col]);
        SOut::st(&Y[(size_t)row*BN + col], y);
      }
    }
  }
}

// Fused attention: one thread per (dst node, head). Online softmax over CSR in-edges.
template<typename SX, typename SKV>
__global__ void attn_gather_kernel(typename SX::T* __restrict__ QA,
                                   const typename SKV::T* __restrict__ K,
                                   const typename SKV::T* __restrict__ V,
                                   const int* __restrict__ rp, const int* __restrict__ slots,
                                   const float* __restrict__ relp, int N){
  int idx = blockIdx.x*256 + threadIdx.x;
  if (idx >= N*8) return;
  int h = idx & 7, n = idx >> 3;
  float q[16];
  SX::ld16(&QA[(size_t)n*128 + h*16], q);
  float scale_h = relp[h]*0.25f;
  float m = -INFINITY, s = 0.f, acc[16];
  #pragma unroll
  for (int i = 0; i < 16; ++i) acc[i] = 0.f;
  int b = rp[n], e = rp[n+1];
  for (int j = b; j < e; ++j){
    int sv = slots[j];
    float kf[16], vf[16];
    SKV::ld16(&K[(size_t)sv*128 + h*16], kf);
    float a = 0.f;
    #pragma unroll
    for (int i = 0; i < 16; ++i) a += q[i]*kf[i];
    a *= scale_h;
    float mn = fmaxf(m, a);
    float c = expf(m - mn);
    float p = expf(a - mn);
    SKV::ld16(&V[(size_t)sv*128 + h*16], vf);
    s = s*c + p;
    #pragma unroll
    for (int i = 0; i < 16; ++i) acc[i] = acc[i]*c + p*vf[i];
    m = mn;
  }
  float inv = 1.f/(s + 1e-16f);
  #pragma unroll
  for (int i = 0; i < 16; ++i) SX::st(&QA[(size_t)n*128 + h*16 + i], acc[i]*inv);
}

struct Ptrs {
  const float *x_author, *x_paper, *win_w, *win_b, *kqv_w, *kqv_b, *a_w, *a_b;
  const float *skip, *rel_a, *rel_m, *rel_p, *out_w, *out_b;
  const int *src0, *dst0, *src1, *dst1;
};

static void run_pipeline(const Ptrs& P, float* d_out, char* ws, hipStream_t stream){
  using SX = StF32;    // X / Q / agg storage: fp32 (accuracy headroom)
  using SKV = StBF16;  // K / V storage: bf16
  size_t off = 0;
  auto alloc = [&](size_t bytes) -> void* {
    void* p = ws + off;
    off += (bytes + 255) & ~(size_t)255;
    return p;
  };
  float* X0 = (float*)alloc((size_t)Na*128*4);
  float* X1 = (float*)alloc((size_t)Np*128*4);
  float* Q0 = (float*)alloc((size_t)Na*128*4);   // Q -> agg in place
  float* Q1 = (float*)alloc((size_t)Np*128*4);
  unsigned short* K0 = (unsigned short*)alloc((size_t)Na*128*2);
  unsigned short* K1 = (unsigned short*)alloc((size_t)Np*128*2);
  unsigned short* V0 = (unsigned short*)alloc((size_t)Na*128*2);
  unsigned short* V1 = (unsigned short*)alloc((size_t)Np*128*2);
  float* effw = (float*)alloc((size_t)8*16384*4);
  float* effb = (float*)alloc((size_t)8*128*4);
  unsigned short* wbf = (unsigned short*)alloc((size_t)19*16384*2);
  int* rp0   = (int*)alloc((size_t)(Np+1)*4);
  int* cur0  = (int*)alloc((size_t)Np*4);
  int* slot0 = (int*)alloc((size_t)E*4);
  int* rp1   = (int*)alloc((size_t)(Na+1)*4);
  int* cur1  = (int*)alloc((size_t)Na*4);
  int* slot1 = (int*)alloc((size_t)E*4);
  int* bsum  = (int*)alloc((size_t)1024*4);

  auto cdiv = [](int a, int b){ return (a+b-1)/b; };
  const int geE = cdiv(E, 256);
  const int ga = cdiv(Na, 128), gp = cdiv(Np, 128);
  const int sb0 = cdiv(Np, SCAN_TILE), sb1 = cdiv(Na, SCAN_TILE);

  eff_w_kernel<<<512, 256, 0, stream>>>(P.kqv_w, P.kqv_b, P.rel_a, P.rel_m, effw, effb);

  // weight prep: slots 0-1 win, 2-5 Q(l,t), 6-9 K, 10-13 V, 14-17 a_w, 18 out_w
  PrepSrc ps;
  ps.s[0] = P.win_w; ps.s[1] = P.win_w + 16384;
  for (int l = 0; l < 2; ++l)
    for (int t = 0; t < 2; ++t){
      ps.s[2 + l*2 + t]  = P.kqv_w + (size_t)((l*2+t)*3+1)*16384;
      ps.s[6 + l*2 + t]  = effw + (size_t)(l*4+t*2+0)*16384;
      ps.s[10 + l*2 + t] = effw + (size_t)(l*4+t*2+1)*16384;
      ps.s[14 + l*2 + t] = P.a_w + (size_t)(l*2+t)*16384;
    }
  ps.s[18] = P.out_w;
  prep_w_kernel<<<cdiv(19*16384,256),256,0,stream>>>(ps, wbf);

  // ---- CSR build ----
  zero_int_kernel<<<512,256,0,stream>>>(cur0, Np);
  zero_int_kernel<<<512,256,0,stream>>>(cur1, Na);
  hist_kernel<<<geE,256,0,stream>>>(P.dst0, cur0, E);
  hist_kernel<<<geE,256,0,stream>>>(P.dst1, cur1, E);
  scan_a<<<sb0,256,0,stream>>>(cur0, bsum, Np);
  scan_b<<<1,1024,0,stream>>>(bsum, sb0);
  scan_c<<<sb0,256,0,stream>>>(cur0, bsum, rp0, Np);
  scan_a<<<sb1,256,0,stream>>>(cur1, bsum, Na);
  scan_b<<<1,1024,0,stream>>>(bsum, sb1);
  scan_c<<<sb1,256,0,stream>>>(cur1, bsum, rp1, Na);
  fill_slots_kernel<<<geE,256,0,stream>>>(P.src0, P.dst0, cur0, slot0, E);
  fill_slots_kernel<<<geE,256,0,stream>>>(P.src1, P.dst1, cur1, slot1, E);

  auto W = [&](int s){ return wbf + (size_t)s*16384; };

  // input projections + relu
  gemm_kernel<128,0,1,0,StF32,SX><<<ga,256,0,stream>>>(P.x_author, W(0), P.win_b,     X0, Na, nullptr, nullptr);
  gemm_kernel<128,0,1,0,StF32,SX><<<gp,256,0,stream>>>(P.x_paper,  W(1), P.win_b+128, X1, Np, nullptr, nullptr);

  for (int l = 0; l < L; ++l){
    gemm_kernel<128,0,0,0,SX,SX><<<ga,256,0,stream>>>(X0, W(2+l*2+0), P.kqv_b + ((l*2+0)*3+1)*128, Q0, Na, nullptr, nullptr);
    gemm_kernel<128,0,0,0,SX,SX><<<gp,256,0,stream>>>(X1, W(2+l*2+1), P.kqv_b + ((l*2+1)*3+1)*128, Q1, Np, nullptr, nullptr);
    gemm_kernel<128,0,0,0,SX,SKV><<<ga,256,0,stream>>>(X0, W(6+l*2+0), effb + (l*4+0)*128, K0, Na, nullptr, nullptr);
    gemm_kernel<128,0,0,0,SX,SKV><<<gp,256,0,stream>>>(X1, W(6+l*2+1), effb + (l*4+2)*128, K1, Np, nullptr, nullptr);
    gemm_kernel<128,0,0,0,SX,SKV><<<ga,256,0,stream>>>(X0, W(10+l*2+0), effb + (l*4+1)*128, V0, Na, nullptr, nullptr);
    gemm_kernel<128,0,0,0,SX,SKV><<<gp,256,0,stream>>>(X1, W(10+l*2+1), effb + (l*4+3)*128, V1, Np, nullptr, nullptr);
    attn_gather_kernel<SX,SKV><<<cdiv(Np*8,256),256,0,stream>>>(Q1, K0, V0, rp0, slot0, P.rel_p + (l*2+0)*8, Np);
    attn_gather_kernel<SX,SKV><<<cdiv(Na*8,256),256,0,stream>>>(Q0, K1, V1, rp1, slot1, P.rel_p + (l*2+1)*8, Na);
    gemm_kernel<128,1,0,1,SX,SX><<<ga,256,0,stream>>>(Q0, W(14+l*2+0), P.a_b + (l*2+0)*128, X0, Na, X0, P.skip + (l*2+0));
    gemm_kernel<128,1,0,1,SX,SX><<<gp,256,0,stream>>>(Q1, W(14+l*2+1), P.a_b + (l*2+1)*128, X1, Np, X1, P.skip + (l*2+1));
  }

  gemm_kernel<64,0,0,0,SX,StF32><<<ga,256,0,stream>>>(X0, W(18), P.out_b, d_out, Na, nullptr, nullptr);
}

static size_t plan_bytes(){
  auto al = [](size_t x){ return (x + 255) & ~(size_t)255; };
  size_t t = 0;
  t += 2*(al((size_t)Na*128*4) + al((size_t)Np*128*4));   // X, Q fp32
  t += 2*(al((size_t)Na*128*2) + al((size_t)Np*128*2));   // K, V bf16
  t += al((size_t)8*16384*4) + al((size_t)8*128*4) + al((size_t)19*16384*2);
  t += al((size_t)(Np+1)*4) + al((size_t)Np*4) + al((size_t)E*4);
  t += al((size_t)(Na+1)*4) + al((size_t)Na*4) + al((size_t)E*4);
  t += al((size_t)1024*4);
  return t;
}

} // namespace

extern "C" void kernel_launch(void* const* d_in, const int* in_sizes, int n_in,
                              void* d_out, int out_size, void* d_ws, size_t ws_size,
                              hipStream_t stream){
  Ptrs P;
  P.x_author = (const float*)d_in[0];
  P.x_paper  = (const float*)d_in[1];
  P.win_w = (const float*)d_in[2];
  P.win_b = (const float*)d_in[3];
  P.kqv_w = (const float*)d_in[4];
  P.kqv_b = (const float*)d_in[5];
  P.a_w   = (const float*)d_in[6];
  P.a_b   = (const float*)d_in[7];
  P.skip  = (const float*)d_in[8];
  P.rel_a = (const float*)d_in[9];
  P.rel_m = (const float*)d_in[10];
  P.rel_p = (const float*)d_in[11];
  P.out_w = (const float*)d_in[12];
  P.out_b = (const float*)d_in[13];
  P.src0 = (const int*)d_in[14];
  P.dst0 = (const int*)d_in[15];
  P.src1 = (const int*)d_in[16];
  P.dst1 = (const int*)d_in[17];

  if (ws_size >= plan_bytes()){
    run_pipeline(P, (float*)d_out, (char*)d_ws, stream);
  } else {
    diag_kernel<<<1,1,0,stream>>>((float*)d_out, (float)((double)ws_size/1.0e6));
  }
}

// Round 7
// 442.748 us; speedup vs baseline: 13.3303x; 1.2703x over previous
//
#include <hip/hip_runtime.h>
#include <math.h>

namespace {

constexpr int Na = 50000, Np = 100000, L = 2, E = 150000;
constexpr int SCAN_TILE = 2048;

typedef __attribute__((ext_vector_type(8))) short short8v;
typedef __attribute__((ext_vector_type(4))) float f32x4;

__device__ inline float geluf(float x){ return 0.5f*x*(1.0f + erff(x*0.7071067811865476f)); }

__device__ inline float bf2f(unsigned short u){ return __uint_as_float(((unsigned)u) << 16); }
__device__ inline unsigned short f2bf(float f){
  unsigned u = __float_as_uint(f);
  u += 0x7FFFu + ((u >> 16) & 1u);   // round-to-nearest-even
  return (unsigned short)(u >> 16);
}

struct StF32 {
  using T = float;
  static __device__ float ld(const T* p){ return *p; }
  static __device__ void st(T* p, float v){ *p = v; }
  static __device__ short8v ld8(const T* __restrict__ p){
    float4 lo = *reinterpret_cast<const float4*>(p);
    float4 hi = *reinterpret_cast<const float4*>(p+4);
    short8v v;
    v[0]=(short)f2bf(lo.x); v[1]=(short)f2bf(lo.y); v[2]=(short)f2bf(lo.z); v[3]=(short)f2bf(lo.w);
    v[4]=(short)f2bf(hi.x); v[5]=(short)f2bf(hi.y); v[6]=(short)f2bf(hi.z); v[7]=(short)f2bf(hi.w);
    return v;
  }
  static __device__ void ld16(const T* __restrict__ p, float* o){
    const float4* q = reinterpret_cast<const float4*>(p);
    #pragma unroll
    for (int i = 0; i < 4; ++i){
      float4 v = q[i];
      o[4*i] = v.x; o[4*i+1] = v.y; o[4*i+2] = v.z; o[4*i+3] = v.w;
    }
  }
};
struct StBF16 {
  using T = unsigned short;
  static __device__ float ld(const T* p){ return bf2f(*p); }
  static __device__ void st(T* p, float v){ *p = f2bf(v); }
  static __device__ short8v ld8(const T* __restrict__ p){
    return *reinterpret_cast<const short8v*>(p);
  }
  static __device__ void ld16(const T* __restrict__ p, float* o){
    const uint4* q = reinterpret_cast<const uint4*>(p);
    #pragma unroll
    for (int half = 0; half < 2; ++half){
      uint4 u = q[half];
      o[half*8+0] = bf2f((unsigned short)(u.x & 0xffff));
      o[half*8+1] = bf2f((unsigned short)(u.x >> 16));
      o[half*8+2] = bf2f((unsigned short)(u.y & 0xffff));
      o[half*8+3] = bf2f((unsigned short)(u.y >> 16));
      o[half*8+4] = bf2f((unsigned short)(u.z & 0xffff));
      o[half*8+5] = bf2f((unsigned short)(u.z >> 16));
      o[half*8+6] = bf2f((unsigned short)(u.w & 0xffff));
      o[half*8+7] = bf2f((unsigned short)(u.w >> 16));
    }
  }
};

__global__ void zero_int_kernel(int* __restrict__ p, int n){
  int i = blockIdx.x*256 + threadIdx.x;
  int stride = gridDim.x*256;
  for (; i < n; i += stride) p[i] = 0;
}

__global__ void diag_kernel(float* o, float v){
  if (threadIdx.x == 0 && blockIdx.x == 0) o[0] = v;
}

__global__ void hist_kernel(const int* __restrict__ dst, int* __restrict__ counts, int nE){
  int e = blockIdx.x*256 + threadIdx.x;
  if (e >= nE) return;
  atomicAdd(&counts[dst[e]], 1);
}

// ---- multi-block exclusive scan (3 phases) ----
__global__ void scan_a(const int* __restrict__ counts, int* __restrict__ bsum, int n){
  int base = blockIdx.x*SCAN_TILE;
  int s = 0;
  for (int i = threadIdx.x; i < SCAN_TILE; i += 256){
    int g = base + i;
    s += (g < n) ? counts[g] : 0;
  }
  __shared__ int red[256];
  red[threadIdx.x] = s;
  __syncthreads();
  for (int off = 128; off > 0; off >>= 1){
    if (threadIdx.x < off) red[threadIdx.x] += red[threadIdx.x + off];
    __syncthreads();
  }
  if (threadIdx.x == 0) bsum[blockIdx.x] = red[0];
}

__global__ void scan_b(int* __restrict__ bsum, int nb){
  __shared__ int sh[1024];
  int t = threadIdx.x;
  int v = (t < nb) ? bsum[t] : 0;
  sh[t] = v;
  __syncthreads();
  for (int off = 1; off < 1024; off <<= 1){
    int add = (t >= off) ? sh[t-off] : 0;
    __syncthreads();
    sh[t] += add;
    __syncthreads();
  }
  if (t < nb) bsum[t] = sh[t] - v;   // exclusive
}

__global__ void scan_c(int* __restrict__ counts, const int* __restrict__ bsum,
                       int* __restrict__ rp, int n){
  int base = blockIdx.x*SCAN_TILE;
  __shared__ int sh[SCAN_TILE];
  for (int i = threadIdx.x; i < SCAN_TILE; i += 256){
    int g = base + i;
    sh[i] = (g < n) ? counts[g] : 0;
  }
  __syncthreads();
  int t = threadIdx.x;
  int loc[8], s = 0;
  #pragma unroll
  for (int i = 0; i < 8; ++i){ loc[i] = s; s += sh[t*8 + i]; }
  __shared__ int red[256];
  red[t] = s;
  __syncthreads();
  for (int off = 1; off < 256; off <<= 1){
    int add = (t >= off) ? red[t-off] : 0;
    __syncthreads();
    red[t] += add;
    __syncthreads();
  }
  int texcl = red[t] - s + bsum[blockIdx.x];
  #pragma unroll
  for (int i = 0; i < 8; ++i){
    int g = base + t*8 + i;
    if (g < n){
      int v = texcl + loc[i];
      rp[g] = v;
      counts[g] = v;           // cursor for fill pass
      if (g == n-1) rp[n] = v + sh[t*8 + i];
    }
  }
}

__global__ void fill_slots_kernel(const int* __restrict__ src, const int* __restrict__ dst,
                                  int* __restrict__ cursor, int* __restrict__ slots, int nE){
  int e = blockIdx.x*256 + threadIdx.x;
  if (e >= nE) return;
  int slot = atomicAdd(&cursor[dst[e]], 1);
  slots[slot] = src[e];
}

// Fold rel_a/rel_m into K/V projection weights (fp32).
__global__ void eff_w_kernel(const float* __restrict__ kqv_w, const float* __restrict__ kqv_b,
                             const float* __restrict__ rel_a, const float* __restrict__ rel_m,
                             float* __restrict__ effw, float* __restrict__ effb){
  int idx = blockIdx.x*256 + threadIdx.x;
  if (idx >= 2*2*2*128*128) return;
  int j = idx & 127; int f = (idx >> 7) & 127; int c = idx >> 14;
  int kv = c & 1, t = (c >> 1) & 1, l = c >> 2;
  int h = j >> 4, e2 = j & 15;
  int i = (kv == 0) ? 0 : 2;  // K uses i=0, V uses i=2
  const float* W = kqv_w + ((size_t)(((l*2 + t)*3 + i)*128) + f)*128 + h*16;
  const float* A = ((kv == 0) ? rel_a : rel_m) + ((size_t)(l*2 + t)*8 + h)*256;
  float acc = 0.f;
  #pragma unroll
  for (int d = 0; d < 16; ++d) acc += W[d]*A[d*16 + e2];
  effw[(size_t)c*16384 + f*128 + j] = acc;
  if (f == 0){
    const float* B = kqv_b + (size_t)((l*2 + t)*3 + i)*128 + h*16;
    float ab = 0.f;
    #pragma unroll
    for (int d = 0; d < 16; ++d) ab += B[d]*A[d*16 + e2];
    effb[c*128 + j] = ab;
  }
}

// Convert 19 weight matrices fp32 [k][n] -> bf16 transposed [n][128(k)].
struct PrepSrc { const float* s[19]; };
__global__ void prep_w_kernel(PrepSrc P, unsigned short* __restrict__ wbf){
  int idx = blockIdx.x*256 + threadIdx.x;
  if (idx >= 19*16384) return;
  int s = idx >> 14, j = idx & 16383;
  int n = j >> 7, k = j & 127;
  int nc = (s == 18) ? 64 : 128;
  if (n >= nc) return;
  wbf[(size_t)s*16384 + n*128 + k] = f2bf(P.s[s][(size_t)k*nc + n]);
}

// ---------- shared GEMM helpers (XOR-swizzled LDS, 16B granularity) ----------
__device__ inline void stage_w(short* Bs, const unsigned short* __restrict__ WT, int t, int rows){
  for (int c = t; c < rows*16; c += 256){
    int r = c >> 4, c16 = c & 15;
    short8v v = *reinterpret_cast<const short8v*>(&WT[r*128 + c16*8]);
    *reinterpret_cast<short8v*>(&Bs[r*128 + ((c16 ^ (r&7))<<3)]) = v;
  }
}

// MFMA GEMM: Y[N,BN] = epi( act(X[N,128]) @ W[128,BN] + bias ).
template<int BN, int GELU_IN, int RELU_OUT, int SKIP, typename SIn, typename SOut>
__global__ __launch_bounds__(256) void gemm_kernel(
    const typename SIn::T* __restrict__ X,
    const unsigned short* __restrict__ WT,
    const float* __restrict__ bias,
    typename SOut::T* __restrict__ Y, int N,
    const typename SOut::T* __restrict__ skip_x,
    const float* __restrict__ skip_s)
{
  __shared__ __align__(16) short As[128*128];
  __shared__ __align__(16) short Bs[BN*128];
  const int t = threadIdx.x;
  const int row0 = blockIdx.x*128;
  for (int c = t; c < 128*16; c += 256){
    int r = c >> 4, c16 = c & 15;
    int gr = row0 + r;
    short8v v;
    if (gr < N){
      v = SIn::ld8(&X[(size_t)gr*128 + c16*8]);
      if (GELU_IN){
        #pragma unroll
        for (int i = 0; i < 8; ++i){
          float f = geluf(bf2f((unsigned short)v[i]));
          v[i] = (short)f2bf(f);
        }
      }
    } else {
      v = (short8v)0;
    }
    *reinterpret_cast<short8v*>(&As[r*128 + ((c16 ^ (r&7))<<3)]) = v;
  }
  stage_w(Bs, WT, t, BN);
  __syncthreads();
  const int lane = t & 63, wid = t >> 6;
  const int wm = wid >> 1, wn = wid & 1;
  constexpr int NR = BN/32;
  const int lr = lane & 15, lk = lane >> 4;
  f32x4 acc[4][NR] = {};
  #pragma unroll
  for (int kk = 0; kk < 4; ++kk){
    int kc = kk*4 + lk;
    short8v a[4], b[NR];
    #pragma unroll
    for (int m = 0; m < 4; ++m){
      int r = wm*64 + m*16 + lr;
      a[m] = *reinterpret_cast<const short8v*>(&As[r*128 + ((kc ^ (r&7))<<3)]);
    }
    #pragma unroll
    for (int n = 0; n < NR; ++n){
      int r = wn*(BN/2) + n*16 + lr;
      b[n] = *reinterpret_cast<const short8v*>(&Bs[r*128 + ((kc ^ (r&7))<<3)]);
    }
    #pragma unroll
    for (int m = 0; m < 4; ++m)
      #pragma unroll
      for (int n = 0; n < NR; ++n)
        acc[m][n] = __builtin_amdgcn_mfma_f32_16x16x32_bf16(a[m], b[n], acc[m][n], 0, 0, 0);
  }
  float g = 1.f, og = 0.f;
  if (SKIP){ float sv = *skip_s; g = 1.f/(1.f + expf(-sv)); og = 1.f - g; }
  #pragma unroll
  for (int m = 0; m < 4; ++m){
    #pragma unroll
    for (int r = 0; r < 4; ++r){
      int row = row0 + wm*64 + m*16 + lk*4 + r;
      if (row >= N) continue;
      #pragma unroll
      for (int n = 0; n < NR; ++n){
        int col = wn*(BN/2) + n*16 + lr;
        float y = acc[m][n][r] + bias[col];
        if (RELU_OUT) y = fmaxf(y, 0.f);
        if (SKIP) y = g*y + og*SOut::ld(&skip_x[(size_t)row*BN + col]);
        SOut::st(&Y[(size_t)row*BN + col], y);
      }
    }
  }
}

// Fused QKV: stage X tile once, loop over 3 weights, write Q/K/V (bf16).
__global__ __launch_bounds__(256) void qkv_kernel(
    const unsigned short* __restrict__ X,
    const unsigned short* __restrict__ WTq,
    const unsigned short* __restrict__ WTk,
    const unsigned short* __restrict__ WTv,
    const float* __restrict__ bq, const float* __restrict__ bk, const float* __restrict__ bv,
    unsigned short* __restrict__ Q, unsigned short* __restrict__ K, unsigned short* __restrict__ V,
    int N)
{
  __shared__ __align__(16) short As[128*128];
  __shared__ __align__(16) short Bs[128*128];
  const int t = threadIdx.x;
  const int row0 = blockIdx.x*128;
  for (int c = t; c < 128*16; c += 256){
    int r = c >> 4, c16 = c & 15;
    int gr = row0 + r;
    short8v v = (gr < N) ? *reinterpret_cast<const short8v*>(&X[(size_t)gr*128 + c16*8])
                         : (short8v)0;
    *reinterpret_cast<short8v*>(&As[r*128 + ((c16 ^ (r&7))<<3)]) = v;
  }
  const int lane = t & 63, wid = t >> 6;
  const int wm = wid >> 1, wn = wid & 1;
  const int lr = lane & 15, lk = lane >> 4;
  const unsigned short* wts[3] = {WTq, WTk, WTv};
  const float* bias[3] = {bq, bk, bv};
  unsigned short* outs[3] = {Q, K, V};
  for (int s = 0; s < 3; ++s){
    __syncthreads();               // prev compute readers done (covers A staging at s=0)
    stage_w(Bs, wts[s], t, 128);
    __syncthreads();
    f32x4 acc[4][4] = {};
    #pragma unroll
    for (int kk = 0; kk < 4; ++kk){
      int kc = kk*4 + lk;
      short8v a[4], b[4];
      #pragma unroll
      for (int m = 0; m < 4; ++m){
        int r = wm*64 + m*16 + lr;
        a[m] = *reinterpret_cast<const short8v*>(&As[r*128 + ((kc ^ (r&7))<<3)]);
      }
      #pragma unroll
      for (int n = 0; n < 4; ++n){
        int r = wn*64 + n*16 + lr;
        b[n] = *reinterpret_cast<const short8v*>(&Bs[r*128 + ((kc ^ (r&7))<<3)]);
      }
      #pragma unroll
      for (int m = 0; m < 4; ++m)
        #pragma unroll
        for (int n = 0; n < 4; ++n)
          acc[m][n] = __builtin_amdgcn_mfma_f32_16x16x32_bf16(a[m], b[n], acc[m][n], 0, 0, 0);
    }
    const float* bi = bias[s];
    unsigned short* out = outs[s];
    #pragma unroll
    for (int m = 0; m < 4; ++m){
      #pragma unroll
      for (int r = 0; r < 4; ++r){
        int row = row0 + wm*64 + m*16 + lk*4 + r;
        if (row >= N) continue;
        #pragma unroll
        for (int n = 0; n < 4; ++n){
          int col = wn*64 + n*16 + lr;
          out[(size_t)row*128 + col] = f2bf(acc[m][n][r] + bi[col]);
        }
      }
    }
  }
}

// Fused attention: one thread per (dst node, head). Online softmax over CSR in-edges.
__global__ void attn_gather_kernel(unsigned short* __restrict__ QA,
                                   const unsigned short* __restrict__ K,
                                   const unsigned short* __restrict__ V,
                                   const int* __restrict__ rp, const int* __restrict__ slots,
                                   const float* __restrict__ relp, int N){
  int idx = blockIdx.x*256 + threadIdx.x;
  if (idx >= N*8) return;
  int h = idx & 7, n = idx >> 3;
  float q[16];
  StBF16::ld16(&QA[(size_t)n*128 + h*16], q);
  float scale_h = relp[h]*0.25f;
  float m = -INFINITY, s = 0.f, acc[16];
  #pragma unroll
  for (int i = 0; i < 16; ++i) acc[i] = 0.f;
  int b = rp[n], e = rp[n+1];
  for (int j = b; j < e; ++j){
    int sv = slots[j];
    float kf[16], vf[16];
    StBF16::ld16(&K[(size_t)sv*128 + h*16], kf);
    float a = 0.f;
    #pragma unroll
    for (int i = 0; i < 16; ++i) a += q[i]*kf[i];
    a *= scale_h;
    float mn = fmaxf(m, a);
    float c = expf(m - mn);
    float p = expf(a - mn);
    StBF16::ld16(&V[(size_t)sv*128 + h*16], vf);
    s = s*c + p;
    #pragma unroll
    for (int i = 0; i < 16; ++i) acc[i] = acc[i]*c + p*vf[i];
    m = mn;
  }
  float inv = 1.f/(s + 1e-16f);
  #pragma unroll
  for (int i = 0; i < 16; ++i) QA[(size_t)n*128 + h*16 + i] = f2bf(acc[i]*inv);
}

struct Ptrs {
  const float *x_author, *x_paper, *win_w, *win_b, *kqv_w, *kqv_b, *a_w, *a_b;
  const float *skip, *rel_a, *rel_m, *rel_p, *out_w, *out_b;
  const int *src0, *dst0, *src1, *dst1;
};

static void run_pipeline(const Ptrs& P, float* d_out, char* ws, hipStream_t stream){
  using BF = unsigned short;
  size_t off = 0;
  auto alloc = [&](size_t bytes) -> void* {
    void* p = ws + off;
    off += (bytes + 255) & ~(size_t)255;
    return p;
  };
  BF* X0 = (BF*)alloc((size_t)Na*128*2);
  BF* X1 = (BF*)alloc((size_t)Np*128*2);
  BF* Q0 = (BF*)alloc((size_t)Na*128*2);   // Q -> agg in place
  BF* Q1 = (BF*)alloc((size_t)Np*128*2);
  BF* K0 = (BF*)alloc((size_t)Na*128*2);
  BF* K1 = (BF*)alloc((size_t)Np*128*2);
  BF* V0 = (BF*)alloc((size_t)Na*128*2);
  BF* V1 = (BF*)alloc((size_t)Np*128*2);
  float* effw = (float*)alloc((size_t)8*16384*4);
  float* effb = (float*)alloc((size_t)8*128*4);
  BF* wbf = (BF*)alloc((size_t)19*16384*2);
  int* rp0   = (int*)alloc((size_t)(Np+1)*4);
  int* cur0  = (int*)alloc((size_t)Np*4);
  int* slot0 = (int*)alloc((size_t)E*4);
  int* rp1   = (int*)alloc((size_t)(Na+1)*4);
  int* cur1  = (int*)alloc((size_t)Na*4);
  int* slot1 = (int*)alloc((size_t)E*4);
  int* bsum  = (int*)alloc((size_t)1024*4);

  auto cdiv = [](int a, int b){ return (a+b-1)/b; };
  const int geE = cdiv(E, 256);
  const int ga = cdiv(Na, 128), gp = cdiv(Np, 128);
  const int sb0 = cdiv(Np, SCAN_TILE), sb1 = cdiv(Na, SCAN_TILE);

  eff_w_kernel<<<512, 256, 0, stream>>>(P.kqv_w, P.kqv_b, P.rel_a, P.rel_m, effw, effb);

  // weight prep: slots 0-1 win, 2-5 Q(l,t), 6-9 K, 10-13 V, 14-17 a_w, 18 out_w
  PrepSrc ps;
  ps.s[0] = P.win_w; ps.s[1] = P.win_w + 16384;
  for (int l = 0; l < 2; ++l)
    for (int t = 0; t < 2; ++t){
      ps.s[2 + l*2 + t]  = P.kqv_w + (size_t)((l*2+t)*3+1)*16384;
      ps.s[6 + l*2 + t]  = effw + (size_t)(l*4+t*2+0)*16384;
      ps.s[10 + l*2 + t] = effw + (size_t)(l*4+t*2+1)*16384;
      ps.s[14 + l*2 + t] = P.a_w + (size_t)(l*2+t)*16384;
    }
  ps.s[18] = P.out_w;
  prep_w_kernel<<<cdiv(19*16384,256),256,0,stream>>>(ps, wbf);

  // ---- CSR build ----
  zero_int_kernel<<<512,256,0,stream>>>(cur0, Np);
  zero_int_kernel<<<512,256,0,stream>>>(cur1, Na);
  hist_kernel<<<geE,256,0,stream>>>(P.dst0, cur0, E);
  hist_kernel<<<geE,256,0,stream>>>(P.dst1, cur1, E);
  scan_a<<<sb0,256,0,stream>>>(cur0, bsum, Np);
  scan_b<<<1,1024,0,stream>>>(bsum, sb0);
  scan_c<<<sb0,256,0,stream>>>(cur0, bsum, rp0, Np);
  scan_a<<<sb1,256,0,stream>>>(cur1, bsum, Na);
  scan_b<<<1,1024,0,stream>>>(bsum, sb1);
  scan_c<<<sb1,256,0,stream>>>(cur1, bsum, rp1, Na);
  fill_slots_kernel<<<geE,256,0,stream>>>(P.src0, P.dst0, cur0, slot0, E);
  fill_slots_kernel<<<geE,256,0,stream>>>(P.src1, P.dst1, cur1, slot1, E);

  auto W = [&](int s){ return wbf + (size_t)s*16384; };

  // input projections + relu (fp32 in, bf16 out)
  gemm_kernel<128,0,1,0,StF32,StBF16><<<ga,256,0,stream>>>(P.x_author, W(0), P.win_b,     X0, Na, nullptr, nullptr);
  gemm_kernel<128,0,1,0,StF32,StBF16><<<gp,256,0,stream>>>(P.x_paper,  W(1), P.win_b+128, X1, Np, nullptr, nullptr);

  for (int l = 0; l < L; ++l){
    qkv_kernel<<<ga,256,0,stream>>>(X0, W(2+l*2+0), W(6+l*2+0), W(10+l*2+0),
                                    P.kqv_b + ((l*2+0)*3+1)*128, effb + (l*4+0)*128, effb + (l*4+1)*128,
                                    Q0, K0, V0, Na);
    qkv_kernel<<<gp,256,0,stream>>>(X1, W(2+l*2+1), W(6+l*2+1), W(10+l*2+1),
                                    P.kqv_b + ((l*2+1)*3+1)*128, effb + (l*4+2)*128, effb + (l*4+3)*128,
                                    Q1, K1, V1, Np);
    attn_gather_kernel<<<cdiv(Np*8,256),256,0,stream>>>(Q1, K0, V0, rp0, slot0, P.rel_p + (l*2+0)*8, Np);
    attn_gather_kernel<<<cdiv(Na*8,256),256,0,stream>>>(Q0, K1, V1, rp1, slot1, P.rel_p + (l*2+1)*8, Na);
    gemm_kernel<128,1,0,1,StBF16,StBF16><<<ga,256,0,stream>>>(Q0, W(14+l*2+0), P.a_b + (l*2+0)*128, X0, Na, X0, P.skip + (l*2+0));
    gemm_kernel<128,1,0,1,StBF16,StBF16><<<gp,256,0,stream>>>(Q1, W(14+l*2+1), P.a_b + (l*2+1)*128, X1, Np, X1, P.skip + (l*2+1));
  }

  gemm_kernel<64,0,0,0,StBF16,StF32><<<ga,256,0,stream>>>(X0, W(18), P.out_b, d_out, Na, nullptr, nullptr);
}

static size_t plan_bytes(){
  auto al = [](size_t x){ return (x + 255) & ~(size_t)255; };
  size_t t = 0;
  t += 4*(al((size_t)Na*128*2) + al((size_t)Np*128*2));   // X,Q,K,V bf16
  t += al((size_t)8*16384*4) + al((size_t)8*128*4) + al((size_t)19*16384*2);
  t += al((size_t)(Np+1)*4) + al((size_t)Np*4) + al((size_t)E*4);
  t += al((size_t)(Na+1)*4) + al((size_t)Na*4) + al((size_t)E*4);
  t += al((size_t)1024*4);
  return t;
}

} // namespace

extern "C" void kernel_launch(void* const* d_in, const int* in_sizes, int n_in,
                              void* d_out, int out_size, void* d_ws, size_t ws_size,
                              hipStream_t stream){
  Ptrs P;
  P.x_author = (const float*)d_in[0];
  P.x_paper  = (const float*)d_in[1];
  P.win_w = (const float*)d_in[2];
  P.win_b = (const float*)d_in[3];
  P.kqv_w = (const float*)d_in[4];
  P.kqv_b = (const float*)d_in[5];
  P.a_w   = (const float*)d_in[6];
  P.a_b   = (const float*)d_in[7];
  P.skip  = (const float*)d_in[8];
  P.rel_a = (const float*)d_in[9];
  P.rel_m = (const float*)d_in[10];
  P.rel_p = (const float*)d_in[11];
  P.out_w = (const float*)d_in[12];
  P.out_b = (const float*)d_in[13];
  P.src0 = (const int*)d_in[14];
  P.dst0 = (const int*)d_in[15];
  P.src1 = (const int*)d_in[16];
  P.dst1 = (const int*)d_in[17];

  if (ws_size >= plan_bytes()){
    run_pipeline(P, (float*)d_out, (char*)d_ws, stream);
  } else {
    diag_kernel<<<1,1,0,stream>>>((float*)d_out, (float)((double)ws_size/1.0e6));
  }
}